// Round 7
// baseline (1591.944 us; speedup 1.0000x reference)
//
#include <hip/hip_runtime.h>
#include <hip/hip_bf16.h>

#define BN_RSQ 0.9999950000374997f  // 1/sqrt(1+1e-5)

// ---------------------------------------------------------------------------
// Prefold BN into conv weights: wf = w*g*rsq, bf = b*g*rsq + a.
// ---------------------------------------------------------------------------
struct LayerP {
  const float* w; const float* b; const float* g; const float* a;
  float* wf; float* bf; int cout; int cin;
};
struct AllP { LayerP L[7]; };

__global__ void prefold_kernel(AllP A) {
  LayerP p = A.L[blockIdx.y];
  int n = p.cout * p.cin * 9;
  int i = blockIdx.x * 256 + threadIdx.x;
  if (i < n) {
    int o = i / (p.cin * 9);
    p.wf[i] = p.w[i] * p.g[o] * BN_RSQ;
  }
  if (i < p.cout) p.bf[i] = p.b[i] * p.g[i] * BN_RSQ + p.a[i];
}

// ---------------------------------------------------------------------------
// 3x3 SAME conv (+folded BN) + ReLU.
//   Tile: TX x 16 output px per block (256 threads; thread = TX/16 x-px).
//   Staging is ROW-BASED (wave = rows, lane = x; no x-bounds on interior) and
//   LOAD-BATCHED: phase A issues a whole group's global loads into registers
//   (fixed-trip unrolled), phase B combines + ds_writes. One latency exposure
//   per group instead of per pass (in-order issue: per-pass waitcnt was
//   serializing ~400cyc x 9-18 passes x chunks).  History: r4 cross-barrier
//   prefetch -> VGPR 248, regressed; r5 row-based staging cut staging VALU;
//   r6 showed residual = exposed latency, fixed here. CHUNK=8 on low-res
//   layers halves barrier count (LDS <=33KB keeps 4 blocks/CU).
//   - CIN1 ch from in1 (POOL_IN: 2x2 maxpool on the fly, in1 is [.,.,2H,2W]),
//     CIN2 ch from in2 (UP_IN2: bilinear 2x upsample align_corners=True,
//     in2 is [B,CIN2,H/2,W/2]).
//   - OSPLIT: output-channel split across blocks (blockIdx.z = og*8 + batch).
//   - FUSE_OUT: 1x1 conv + sigmoid epilogue (requires OSPLIT==1).
// ---------------------------------------------------------------------------
template <int CIN1, int CIN2, int COUTG, int OSPLIT, int TX, int CHUNKP,
          bool POOL_IN, bool UP_IN2, bool FUSE_OUT>
__launch_bounds__(256)
__global__ void conv3x3_cbr(const float* __restrict__ in1,
                            const float* __restrict__ in2,
                            const float* __restrict__ wf,
                            const float* __restrict__ bf,
                            const float* __restrict__ wout,
                            const float* __restrict__ bout,
                            float* __restrict__ out, int H, int W) {
  constexpr int CIN = CIN1 + CIN2;
  constexpr int COUT = COUTG * OSPLIT;
  constexpr int PPT = TX / 16;        // px per thread (2 or 4)
  constexpr int CHUNK = (CIN < CHUNKP) ? CIN : CHUNKP;
  constexpr int XT = TX + 2;          // tile x extent
  constexpr int XS = TX + 4;          // tile x stride
  constexpr int YT = 18;              // tile y extent
  constexpr int ROWS = CHUNK * YT;    // rows per chunk
  constexpr int RPW = (TX == 64) ? 1 : 2;        // rows per wave-pass
  constexpr int NPASS = (ROWS + 4 * RPW - 1) / (4 * RPW);  // passes per wave
  constexpr bool GUARD = (ROWS % (4 * RPW)) != 0;
  constexpr int BG = (POOL_IN || UP_IN2) ? ((NPASS < 9) ? NPASS : 9) : NPASS;
  constexpr int NG = (NPASS + BG - 1) / BG;      // load groups
  constexpr int NH = (2 * ROWS + 255) / 256;     // halo passes per thread

  __shared__ float tile[CHUNK][YT][XS];
  __shared__ float wsm[COUTG * CIN * 12];

  const int tid = threadIdx.x;
  const int txp = (tid & 15) * PPT;
  const int ty = tid >> 4;
  const int gx0 = blockIdx.x * TX;
  const int gy0 = blockIdx.y * 16;
  const int b = blockIdx.z & 7;
  const int og = blockIdx.z >> 3;
  const int obase = og * COUTG;

  const int lane = tid & 63;
  const int wv = tid >> 6;                         // wave id 0..3
  const int sub = (TX == 64) ? 0 : (lane >> 5);    // row-within-pass
  const int xl = (TX == 64) ? lane : (lane & 31);  // 0..TX-1
  const int ixi = gx0 + xl;                        // interior global x (valid)

  const int Hi = H >> 1, Wi = W >> 1;
  const float syf = UP_IN2 ? (float)(Hi - 1) / (float)(H - 1) : 0.f;

  // hoisted per-lane x-params for the upsample path
  int ux0 = 0, ux1 = 0;
  float uwx = 0.f;
  if (UP_IN2) {
    const float sx = (float)(Wi - 1) / (float)(W - 1);
    float fx = ixi * sx;
    ux0 = (int)fx;
    ux1 = min(ux0 + 1, Wi - 1);
    uwx = fx - (float)ux0;
  }

  // ---- stage ALL folded weights once ----
  for (int idx = tid; idx < COUTG * CIN * 9; idx += 256) {
    int o = idx / (CIN * 9);
    int r = idx - o * (CIN * 9);
    int c = r / 9;
    int t = r - c * 9;
    wsm[(o * CIN + c) * 12 + t] = wf[((obase + o) * CIN + c) * 9 + t];
  }

  float acc[COUTG][PPT];
#pragma unroll
  for (int o = 0; o < COUTG; ++o)
#pragma unroll
    for (int i = 0; i < PPT; ++i) acc[o][i] = 0.f;

  for (int cc = 0; cc < CIN; cc += CHUNK) {
    __syncthreads();
    // ======== interior rows: batched two-phase staging ========
#pragma unroll
    for (int g = 0; g < NG; ++g) {
      float l0[BG], l1[BG], l2[BG], l3[BG], lw[BG];
      // ---- phase A: issue all loads of this group ----
#pragma unroll
      for (int k = 0; k < BG; ++k) {
        const int pp = g * BG + k;
        if (pp < NPASS) {
          const int row = (wv + 4 * pp) * RPW + sub;
          if (!GUARD || row < ROWS) {
            const int c = row / YT;
            const int yy = row - c * YT;
            const int iy = gy0 + yy - 1;
            const int cg = cc + c;
            if (iy >= 0 && iy < H) {
              if (CIN2 == 0 || cg < CIN1) {
                const int cb = b * CIN1 + cg;
                if (POOL_IN) {
                  const float* p = in1 + (size_t)(cb * 2 * H + 2 * iy) * (2 * W) + 2 * ixi;
                  float2 t0 = *(const float2*)p;
                  float2 t1 = *(const float2*)(p + 2 * W);
                  l0[k] = t0.x; l1[k] = t0.y; l2[k] = t1.x; l3[k] = t1.y;
                } else {
                  l0[k] = in1[(size_t)(cb * H + iy) * W + ixi];
                }
              } else if (UP_IN2) {
                const int cb = b * CIN2 + (cg - CIN1);
                float fy = iy * syf;
                int y0 = (int)fy;
                int y1 = min(y0 + 1, Hi - 1);
                lw[k] = fy - (float)y0;
                const float* r0p = in2 + (size_t)(cb * Hi + y0) * Wi;
                const float* r1p = in2 + (size_t)(cb * Hi + y1) * Wi;
                l0[k] = r0p[ux0]; l1[k] = r0p[ux1];
                l2[k] = r1p[ux0]; l3[k] = r1p[ux1];
              } else {
                const int cb = b * CIN2 + (cg - CIN1);
                l0[k] = in2[(size_t)(cb * H + iy) * W + ixi];
              }
            }
          }
        }
      }
      // ---- phase B: combine + ds_write ----
#pragma unroll
      for (int k = 0; k < BG; ++k) {
        const int pp = g * BG + k;
        if (pp < NPASS) {
          const int row = (wv + 4 * pp) * RPW + sub;
          if (!GUARD || row < ROWS) {
            const int c = row / YT;
            const int yy = row - c * YT;
            const int iy = gy0 + yy - 1;
            const int cg = cc + c;
            float v = 0.f;
            if (iy >= 0 && iy < H) {
              if (CIN2 == 0 || cg < CIN1) {
                if (POOL_IN) {
                  v = fmaxf(fmaxf(l0[k], l1[k]), fmaxf(l2[k], l3[k]));
                } else {
                  v = l0[k];
                }
              } else if (UP_IN2) {
                float wy = lw[k];
                float r0 = l0[k] * (1.f - wy) + l2[k] * wy;
                float r1 = l1[k] * (1.f - wy) + l3[k] * wy;
                v = r0 * (1.f - uwx) + r1 * uwx;
              } else {
                v = l0[k];
              }
            }
            tile[c][yy][1 + xl] = v;
          }
        }
      }
    }
    // ======== x-halo columns (2 per row): batched the same way ========
    {
      float h0[NH], h1[NH], h2[NH], h3[NH], hw[NH];
#pragma unroll
      for (int j = 0; j < NH; ++j) {
        const int idx = tid + j * 256;
        if (idx < 2 * ROWS) {
          const int row = idx >> 1;
          const int side = idx & 1;
          const int c = row / YT;
          const int yy = row - c * YT;
          const int iy = gy0 + yy - 1;
          const int ix = side ? (gx0 + TX) : (gx0 - 1);
          const int cg = cc + c;
          if (iy >= 0 && iy < H && ix >= 0 && ix < W) {
            if (CIN2 == 0 || cg < CIN1) {
              const int cb = b * CIN1 + cg;
              if (POOL_IN) {
                const float* p = in1 + (size_t)(cb * 2 * H + 2 * iy) * (2 * W) + 2 * ix;
                h0[j] = p[0]; h1[j] = p[1]; h2[j] = p[2 * W]; h3[j] = p[2 * W + 1];
              } else {
                h0[j] = in1[(size_t)(cb * H + iy) * W + ix];
              }
            } else if (UP_IN2) {
              const int cb = b * CIN2 + (cg - CIN1);
              const float sx = (float)(Wi - 1) / (float)(W - 1);
              float fy = iy * syf, fx = ix * sx;
              int y0 = (int)fy; int y1 = min(y0 + 1, Hi - 1);
              int x0 = (int)fx; int x1 = min(x0 + 1, Wi - 1);
              hw[j] = fy - (float)y0;
              // pack wx into h-regs path: recompute in phase B (cheap, lane-const per ix)
              const float* p = in2 + (size_t)cb * Hi * Wi;
              h0[j] = p[y0 * Wi + x0]; h1[j] = p[y0 * Wi + x1];
              h2[j] = p[y1 * Wi + x0]; h3[j] = p[y1 * Wi + x1];
            } else {
              const int cb = b * CIN2 + (cg - CIN1);
              h0[j] = in2[(size_t)(cb * H + iy) * W + ix];
            }
          }
        }
      }
#pragma unroll
      for (int j = 0; j < NH; ++j) {
        const int idx = tid + j * 256;
        if (idx < 2 * ROWS) {
          const int row = idx >> 1;
          const int side = idx & 1;
          const int c = row / YT;
          const int yy = row - c * YT;
          const int iy = gy0 + yy - 1;
          const int ix = side ? (gx0 + TX) : (gx0 - 1);
          const int cg = cc + c;
          float v = 0.f;
          if (iy >= 0 && iy < H && ix >= 0 && ix < W) {
            if (CIN2 == 0 || cg < CIN1) {
              if (POOL_IN) v = fmaxf(fmaxf(h0[j], h1[j]), fmaxf(h2[j], h3[j]));
              else         v = h0[j];
            } else if (UP_IN2) {
              const float sx = (float)(Wi - 1) / (float)(W - 1);
              float fx = ix * sx;
              int x0 = (int)fx;
              float wx = fx - (float)x0;
              float wy = hw[j];
              float r0 = h0[j] * (1.f - wy) + h2[j] * wy;
              float r1 = h1[j] * (1.f - wy) + h3[j] * wy;
              v = r0 * (1.f - wx) + r1 * wx;
            } else {
              v = h0[j];
            }
          }
          tile[c][yy][side ? (TX + 1) : 0] = v;
        }
      }
    }
    __syncthreads();
    // ======== compute from LDS: vector reads + FMAs ========
#pragma unroll
    for (int c = 0; c < CHUNK; ++c) {
      float rr[3][PPT + 2];
#pragma unroll
      for (int dy = 0; dy < 3; ++dy) {
        const float* p = &tile[c][ty + dy][txp];
        if (PPT == 4) {
          float4 a4 = *(const float4*)p;        // 16B aligned
          float2 b2 = *(const float2*)(p + 4);  // 8B aligned
          rr[dy][0] = a4.x; rr[dy][1] = a4.y; rr[dy][2] = a4.z; rr[dy][3] = a4.w;
          rr[dy][4] = b2.x; rr[dy][5] = b2.y;
        } else {
          float2 a2 = *(const float2*)p;        // 8B aligned
          float2 b2 = *(const float2*)(p + 2);
          rr[dy][0] = a2.x; rr[dy][1] = a2.y; rr[dy][2] = b2.x; rr[dy][3] = b2.y;
        }
      }
      const int cabs = cc + c;
#pragma unroll
      for (int o = 0; o < COUTG; ++o) {
        const float4* wp = (const float4*)&wsm[(o * CIN + cabs) * 12];
        float4 wa = wp[0];
        float4 wb = wp[1];
        float w8 = wsm[(o * CIN + cabs) * 12 + 8];
#pragma unroll
        for (int i = 0; i < PPT; ++i) {
          float s = acc[o][i];
          s = fmaf(rr[0][i + 0], wa.x, s);
          s = fmaf(rr[0][i + 1], wa.y, s);
          s = fmaf(rr[0][i + 2], wa.z, s);
          s = fmaf(rr[1][i + 0], wa.w, s);
          s = fmaf(rr[1][i + 1], wb.x, s);
          s = fmaf(rr[1][i + 2], wb.y, s);
          s = fmaf(rr[2][i + 0], wb.z, s);
          s = fmaf(rr[2][i + 1], wb.w, s);
          s = fmaf(rr[2][i + 2], w8, s);
          acc[o][i] = s;
        }
      }
    }
  }

  const int oy = gy0 + ty;
  const int ox = gx0 + txp;
  if (FUSE_OUT) {
    float sv[PPT];
#pragma unroll
    for (int i = 0; i < PPT; ++i) sv[i] = bout[0];
#pragma unroll
    for (int o = 0; o < COUTG; ++o) {
      float bo = bf[obase + o], wo = wout[o];
#pragma unroll
      for (int i = 0; i < PPT; ++i) {
        float rr2 = fmaxf(acc[o][i] + bo, 0.f);
        sv[i] = fmaf(rr2, wo, sv[i]);
      }
    }
#pragma unroll
    for (int i = 0; i < PPT; ++i) sv[i] = 1.f / (1.f + __expf(-sv[i]));
    if (PPT == 4) *(float4*)&out[(b * H + oy) * W + ox] = *(float4*)sv;
    else          *(float2*)&out[(b * H + oy) * W + ox] = *(float2*)sv;
  } else {
#pragma unroll
    for (int o = 0; o < COUTG; ++o) {
      float bo = bf[obase + o];
      float rv[PPT];
#pragma unroll
      for (int i = 0; i < PPT; ++i) rv[i] = fmaxf(acc[o][i] + bo, 0.f);
      float* dst = &out[((b * COUT + obase + o) * H + oy) * W + ox];
      if (PPT == 4) *(float4*)dst = *(float4*)rv;
      else          *(float2*)dst = *(float2*)rv;
    }
  }
}

// ---------------------------------------------------------------------------
// FCAS on the 64x64 channel x4[0,1].
// ---------------------------------------------------------------------------
__global__ void fcas_count_kernel(const float* __restrict__ ch,
                                  const float* __restrict__ w,
                                  const float* __restrict__ bb,
                                  float* __restrict__ scratch) {
  const int H = 64, W = 64, N = H * W;
  __shared__ float vals[N];
  for (int i = threadIdx.x; i < N; i += blockDim.x) vals[i] = ch[i];
  __syncthreads();
  int idx = blockIdx.x * blockDim.x + threadIdx.x;
  if (idx >= N) return;
  float v = vals[idx];
  int p = 0, n = 0, e = 0;
  for (int k = 0; k < N; ++k) {
    float u = vals[k];
    p += (u > v);
    n += (u == v);
    e += (u < v);
  }
  float val = ((float)p * w[0] + bb[0] + (float)n * w[1] + bb[1] +
               (float)e * w[2] + bb[2]) / 3.0f;
  int i = idx >> 6, j = idx & 63;
  bool interior = (i >= 1) && (i <= H - 2) && (j >= 1) && (j <= W - 2);
  scratch[idx] = interior ? val : v;
}

__global__ void fcas_copy_kernel(const float* __restrict__ scratch,
                                 float* __restrict__ ch) {
  int i = blockIdx.x * 256 + threadIdx.x;
  if (i < 4096) ch[i] = scratch[i];
}

// ---------------------------------------------------------------------------
extern "C" void kernel_launch(void* const* d_in, const int* in_sizes, int n_in,
                              void* d_out, int out_size, void* d_ws, size_t ws_size,
                              hipStream_t stream) {
  const float* x      = (const float*)d_in[0];
  const float* w_inc  = (const float*)d_in[1];
  const float* b_inc  = (const float*)d_in[2];
  const float* g_inc  = (const float*)d_in[3];
  const float* a_inc  = (const float*)d_in[4];
  const float* w_d1   = (const float*)d_in[5];
  const float* b_d1   = (const float*)d_in[6];
  const float* g_d1   = (const float*)d_in[7];
  const float* a_d1   = (const float*)d_in[8];
  const float* w_d2   = (const float*)d_in[9];
  const float* b_d2   = (const float*)d_in[10];
  const float* g_d2   = (const float*)d_in[11];
  const float* a_d2   = (const float*)d_in[12];
  const float* w_d3   = (const float*)d_in[13];
  const float* b_d3   = (const float*)d_in[14];
  const float* g_d3   = (const float*)d_in[15];
  const float* a_d3   = (const float*)d_in[16];
  const float* w_u2   = (const float*)d_in[17];
  const float* b_u2   = (const float*)d_in[18];
  const float* g_u2   = (const float*)d_in[19];
  const float* a_u2   = (const float*)d_in[20];
  const float* w_u3   = (const float*)d_in[21];
  const float* b_u3   = (const float*)d_in[22];
  const float* g_u3   = (const float*)d_in[23];
  const float* a_u3   = (const float*)d_in[24];
  const float* w_u4   = (const float*)d_in[25];
  const float* b_u4   = (const float*)d_in[26];
  const float* g_u4   = (const float*)d_in[27];
  const float* a_u4   = (const float*)d_in[28];
  const float* w_out  = (const float*)d_in[29];
  const float* b_out  = (const float*)d_in[30];
  const float* fcas_w = (const float*)d_in[31];
  const float* fcas_b = (const float*)d_in[32];

  float* ws = (float*)d_ws;
  float* x1  = ws;                     // 16,777,216
  float* x2  = x1 + 16777216;          //  8,388,608
  float* x3  = x2 + 8388608;           //  4,194,304
  float* x4  = x3 + 4194304;           //  1,048,576
  float* uo2 = x4 + 1048576;           //  2,097,152
  float* uo3 = uo2 + 2097152;          //  4,194,304
  float* fs  = uo3 + 4194304;          //  4,096
  float* wfp = fs + 4096;
  float* wf_inc = wfp;                 // 216
  float* wf_d1  = wf_inc + 216;        // 1152
  float* wf_d2  = wf_d1 + 1152;        // 4608
  float* wf_d3  = wf_d2 + 4608;        // 9216
  float* wf_u2  = wf_d3 + 9216;        // 9216
  float* wf_u3  = wf_u2 + 9216;        // 2304
  float* wf_u4  = wf_u3 + 2304;        // 576
  float* bf_inc = wf_u4 + 576;         // 8
  float* bf_d1  = bf_inc + 8;          // 16
  float* bf_d2  = bf_d1 + 16;          // 32
  float* bf_d3  = bf_d2 + 32;          // 32
  float* bf_u2  = bf_d3 + 32;          // 16
  float* bf_u3  = bf_u2 + 16;          // 8
  float* bf_u4  = bf_u3 + 8;           // 4
  float* outp = (float*)d_out;

  AllP A;
  A.L[0] = {w_inc, b_inc, g_inc, a_inc, wf_inc, bf_inc, 8, 3};
  A.L[1] = {w_d1, b_d1, g_d1, a_d1, wf_d1, bf_d1, 16, 8};
  A.L[2] = {w_d2, b_d2, g_d2, a_d2, wf_d2, bf_d2, 32, 16};
  A.L[3] = {w_d3, b_d3, g_d3, a_d3, wf_d3, bf_d3, 32, 32};
  A.L[4] = {w_u2, b_u2, g_u2, a_u2, wf_u2, bf_u2, 16, 64};
  A.L[5] = {w_u3, b_u3, g_u3, a_u3, wf_u3, bf_u3, 8, 32};
  A.L[6] = {w_u4, b_u4, g_u4, a_u4, wf_u4, bf_u4, 4, 16};
  prefold_kernel<<<dim3(36, 7), dim3(256), 0, stream>>>(A);

  dim3 blk(256);

  // inc: 3->8 @512, TX=64 (2048 blocks)
  conv3x3_cbr<3, 0, 8, 1, 64, 4, false, false, false><<<dim3(8, 32, 8), blk, 0, stream>>>(
      x, nullptr, wf_inc, bf_inc, nullptr, nullptr, x1, 512, 512);
  // d1: pool(x1) -> 8->16 @256, TX=64, OSPLIT=2 (1024 blocks)
  conv3x3_cbr<8, 0, 8, 2, 64, 4, true, false, false><<<dim3(4, 16, 16), blk, 0, stream>>>(
      x1, nullptr, wf_d1, bf_d1, nullptr, nullptr, x2, 256, 256);
  // d2: pool(x2) -> 16->32 @128, TX=32, CHUNK=8, OSPLIT=8 (2048 blocks)
  conv3x3_cbr<16, 0, 4, 8, 32, 8, true, false, false><<<dim3(4, 8, 64), blk, 0, stream>>>(
      x2, nullptr, wf_d2, bf_d2, nullptr, nullptr, x3, 128, 128);
  // d3: pool(x3) -> 32->32 @64, TX=32, CHUNK=8, OSPLIT=16 (1024 blocks)
  conv3x3_cbr<32, 0, 2, 16, 32, 8, true, false, false><<<dim3(2, 4, 128), blk, 0, stream>>>(
      x3, nullptr, wf_d3, bf_d3, nullptr, nullptr, x4, 64, 64);
  // FCAS on x4[0,1]
  fcas_count_kernel<<<dim3(16), blk, 0, stream>>>(x4 + 4096, fcas_w, fcas_b, fs);
  fcas_copy_kernel<<<dim3(16), blk, 0, stream>>>(fs, x4 + 4096);
  // u2: cat(x3, up2(x4)) 64->16 @128, TX=32, CHUNK=8, OSPLIT=4 (1024 blocks)
  conv3x3_cbr<32, 32, 4, 4, 32, 8, false, true, false><<<dim3(4, 8, 32), blk, 0, stream>>>(
      x3, x4, wf_u2, bf_u2, nullptr, nullptr, uo2, 128, 128);
  // u3: cat(x2, up2(u2out)) 32->8 @256, TX=64, OSPLIT=2 (1024 blocks)
  conv3x3_cbr<16, 16, 4, 2, 64, 4, false, true, false><<<dim3(4, 16, 16), blk, 0, stream>>>(
      x2, uo2, wf_u3, bf_u3, nullptr, nullptr, uo3, 256, 256);
  // u4: cat(x1, up2(u3out)) 16->4 @512, TX=64, fused 1x1+sigmoid (2048 blocks)
  conv3x3_cbr<8, 8, 4, 1, 64, 4, false, true, true><<<dim3(8, 32, 8), blk, 0, stream>>>(
      x1, uo3, wf_u4, bf_u4, w_out, b_out, outp, 512, 512);
}

// Round 8
// 1000.266 us; speedup vs baseline: 1.5915x; 1.5915x over previous
//
#include <hip/hip_runtime.h>
#include <hip/hip_bf16.h>

#define BN_RSQ 0.9999950000374997f  // 1/sqrt(1+1e-5)

// ---------------------------------------------------------------------------
// Prefold BN into conv weights: wf = w*g*rsq, bf = b*g*rsq + a.
// ---------------------------------------------------------------------------
struct LayerP {
  const float* w; const float* b; const float* g; const float* a;
  float* wf; float* bf; int cout; int cin;
};
struct AllP { LayerP L[7]; };

__global__ void prefold_kernel(AllP A) {
  LayerP p = A.L[blockIdx.y];
  int n = p.cout * p.cin * 9;
  int i = blockIdx.x * 256 + threadIdx.x;
  if (i < n) {
    int o = i / (p.cin * 9);
    p.wf[i] = p.w[i] * p.g[o] * BN_RSQ;
  }
  if (i < p.cout) p.bf[i] = p.b[i] * p.g[i] * BN_RSQ + p.a[i];
}

// ---------------------------------------------------------------------------
// 3x3 SAME conv (+folded BN) + ReLU.
//   Tile: TX x 16 output px per block (256 threads; thread = TX/16 x-px).
//   Staging: ROW-BASED (wave = rows, lane = x; no x-bounds interior) with
//   PAIR-UNROLL (BG=2): two passes' independent global loads issue together,
//   then both combine+ds_write. One latency exposure per 2 passes at ~12
//   extra VGPRs.  History: r4 cross-barrier prefetch -> VGPR 248 regress;
//   r6 per-pass staging = exposed latency; r7 BG=9..18 batching -> VGPR 256 +
//   scratch spills (632MB writes) -> 2.4x regress. BG=2 is the register-safe
//   middle. Out-of-range rows load zeros; all combines map 0->0, so phase B
//   needs no y-recheck.
//   - CIN1 ch from in1 (POOL_IN: 2x2 maxpool on the fly, in1 is [.,.,2H,2W]),
//     CIN2 ch from in2 (UP_IN2: bilinear 2x upsample align_corners=True,
//     in2 is [B,CIN2,H/2,W/2]).
//   - OSPLIT: output-channel split across blocks (blockIdx.z = og*8 + batch).
//   - FUSE_OUT: 1x1 conv + sigmoid epilogue (requires OSPLIT==1).
// ---------------------------------------------------------------------------
template <int CIN1, int CIN2, int COUTG, int OSPLIT, int TX, int CHUNKP,
          bool POOL_IN, bool UP_IN2, bool FUSE_OUT>
__launch_bounds__(256)
__global__ void conv3x3_cbr(const float* __restrict__ in1,
                            const float* __restrict__ in2,
                            const float* __restrict__ wf,
                            const float* __restrict__ bf,
                            const float* __restrict__ wout,
                            const float* __restrict__ bout,
                            float* __restrict__ out, int H, int W) {
  constexpr int CIN = CIN1 + CIN2;
  constexpr int COUT = COUTG * OSPLIT;
  constexpr int PPT = TX / 16;        // px per thread (2 or 4)
  constexpr int CHUNK = (CIN < CHUNKP) ? CIN : CHUNKP;
  constexpr int XT = TX + 2;          // tile x extent
  constexpr int XS = TX + 4;          // tile x stride
  constexpr int YT = 18;              // tile y extent
  constexpr int ROWS = CHUNK * YT;    // rows per chunk
  constexpr int RPW = (TX == 64) ? 1 : 2;                  // rows per pass
  constexpr int NPASS = (ROWS + 4 * RPW - 1) / (4 * RPW);  // passes per wave
  constexpr bool GUARD = (ROWS % (4 * RPW)) != 0;

  __shared__ float tile[CHUNK][YT][XS];
  __shared__ float wsm[COUTG * CIN * 12];

  const int tid = threadIdx.x;
  const int txp = (tid & 15) * PPT;
  const int ty = tid >> 4;
  const int gx0 = blockIdx.x * TX;
  const int gy0 = blockIdx.y * 16;
  const int b = blockIdx.z & 7;
  const int og = blockIdx.z >> 3;
  const int obase = og * COUTG;

  const int lane = tid & 63;
  const int wv = tid >> 6;                         // wave id 0..3
  const int sub = (TX == 64) ? 0 : (lane >> 5);    // row-within-pass
  const int xl = (TX == 64) ? lane : (lane & 31);  // 0..TX-1
  const int ixi = gx0 + xl;                        // interior global x (valid)

  const int Hi = H >> 1, Wi = W >> 1;
  const float syf = UP_IN2 ? (float)(Hi - 1) / (float)(H - 1) : 0.f;

  // hoisted per-lane x-params for the upsample path
  int ux0 = 0, ux1 = 0;
  float uwx = 0.f;
  if (UP_IN2) {
    const float sx = (float)(Wi - 1) / (float)(W - 1);
    float fx = ixi * sx;
    ux0 = (int)fx;
    ux1 = min(ux0 + 1, Wi - 1);
    uwx = fx - (float)ux0;
  }

  // ---- stage ALL folded weights once ----
  for (int idx = tid; idx < COUTG * CIN * 9; idx += 256) {
    int o = idx / (CIN * 9);
    int r = idx - o * (CIN * 9);
    int c = r / 9;
    int t = r - c * 9;
    wsm[(o * CIN + c) * 12 + t] = wf[((obase + o) * CIN + c) * 9 + t];
  }

  float acc[COUTG][PPT];
#pragma unroll
  for (int o = 0; o < COUTG; ++o)
#pragma unroll
    for (int i = 0; i < PPT; ++i) acc[o][i] = 0.f;

  for (int cc = 0; cc < CIN; cc += CHUNK) {
    __syncthreads();

    // phase A: issue one row's loads (zeros if y out of range)
    auto issueRow = [&](int row, float4& L, float& LW, int& C, int& YY) {
      const int c = row / YT;
      const int yy = row - c * YT;
      const int iy = gy0 + yy - 1;
      C = c; YY = yy;
      L.x = 0.f; L.y = 0.f; L.z = 0.f; L.w = 0.f; LW = 0.f;
      if (iy >= 0 && iy < H) {
        const int cg = cc + c;
        if (CIN2 == 0 || cg < CIN1) {
          const int cb = b * CIN1 + cg;
          if (POOL_IN) {
            const float* p = in1 + (size_t)(cb * 2 * H + 2 * iy) * (2 * W) + 2 * ixi;
            float2 t0 = *(const float2*)p;
            float2 t1 = *(const float2*)(p + 2 * W);
            L.x = t0.x; L.y = t0.y; L.z = t1.x; L.w = t1.y;
          } else {
            L.x = in1[(size_t)(cb * H + iy) * W + ixi];
          }
        } else if (UP_IN2) {
          const int cb = b * CIN2 + (cg - CIN1);
          float fy = iy * syf;
          int y0 = (int)fy;
          int y1 = min(y0 + 1, Hi - 1);
          LW = fy - (float)y0;
          const float* r0p = in2 + (size_t)(cb * Hi + y0) * Wi;
          const float* r1p = in2 + (size_t)(cb * Hi + y1) * Wi;
          L.x = r0p[ux0]; L.y = r0p[ux1];
          L.z = r1p[ux0]; L.w = r1p[ux1];
        } else {
          const int cb = b * CIN2 + (cg - CIN1);
          L.x = in2[(size_t)(cb * H + iy) * W + ixi];
        }
      }
    };
    // phase B: combine + ds_write (all combines map zeros -> 0)
    auto commitRow = [&](float4 L, float LW, int C, int YY) {
      const int cg = cc + C;
      float v;
      if (CIN2 == 0 || cg < CIN1) {
        v = POOL_IN ? fmaxf(fmaxf(L.x, L.y), fmaxf(L.z, L.w)) : L.x;
      } else if (UP_IN2) {
        float r0 = L.x * (1.f - LW) + L.z * LW;
        float r1 = L.y * (1.f - LW) + L.w * LW;
        v = r0 * (1.f - uwx) + r1 * uwx;
      } else {
        v = L.x;
      }
      tile[C][YY][1 + xl] = v;
    };

    // ---- interior rows: pair-unrolled (BG=2) ----
#pragma unroll
    for (int g = 0; g < NPASS; g += 2) {
      float4 La, Lb; float Wa = 0.f, Wb = 0.f;
      int Ca = 0, YYa = 0, Cb = 0, YYb = 0;
      const int rowA = (wv + 4 * g) * RPW + sub;
      const int rowB = (wv + 4 * (g + 1)) * RPW + sub;
      const bool okA = !GUARD || rowA < ROWS;
      const bool okB = (g + 1 < NPASS) && (!GUARD || rowB < ROWS);
      if (okA) issueRow(rowA, La, Wa, Ca, YYa);
      if (okB) issueRow(rowB, Lb, Wb, Cb, YYb);
      if (okA) commitRow(La, Wa, Ca, YYa);
      if (okB) commitRow(Lb, Wb, Cb, YYb);
    }

    // ---- x-halo columns (2 per row, <=2 passes of 256 threads) ----
    for (int idx = tid; idx < 2 * ROWS; idx += 256) {
      const int row = idx >> 1;
      const int side = idx & 1;
      const int c = row / YT;
      const int yy = row - c * YT;
      const int iy = gy0 + yy - 1;
      const int ix = side ? (gx0 + TX) : (gx0 - 1);
      const int cg = cc + c;
      float v = 0.f;
      if (iy >= 0 && iy < H && ix >= 0 && ix < W) {
        if (CIN2 == 0 || cg < CIN1) {
          const int cb = b * CIN1 + cg;
          if (POOL_IN) {
            const float* p = in1 + (size_t)(cb * 2 * H + 2 * iy) * (2 * W) + 2 * ix;
            v = fmaxf(fmaxf(p[0], p[1]), fmaxf(p[2 * W], p[2 * W + 1]));
          } else {
            v = in1[(size_t)(cb * H + iy) * W + ix];
          }
        } else if (UP_IN2) {
          const int cb = b * CIN2 + (cg - CIN1);
          const float sx = (float)(Wi - 1) / (float)(W - 1);
          float fy = iy * syf, fx = ix * sx;
          int y0 = (int)fy; int y1 = min(y0 + 1, Hi - 1);
          int x0 = (int)fx; int x1 = min(x0 + 1, Wi - 1);
          float wy = fy - (float)y0, wx = fx - (float)x0;
          const float* p = in2 + (size_t)cb * Hi * Wi;
          float a00 = p[y0 * Wi + x0], a01 = p[y0 * Wi + x1];
          float a10 = p[y1 * Wi + x0], a11 = p[y1 * Wi + x1];
          float r0 = a00 * (1.f - wy) + a10 * wy;
          float r1 = a01 * (1.f - wy) + a11 * wy;
          v = r0 * (1.f - wx) + r1 * wx;
        } else {
          const int cb = b * CIN2 + (cg - CIN1);
          v = in2[(size_t)(cb * H + iy) * W + ix];
        }
      }
      tile[c][yy][side ? (TX + 1) : 0] = v;
    }
    __syncthreads();

    // ---- compute from LDS: vector reads + FMAs ----
#pragma unroll
    for (int c = 0; c < CHUNK; ++c) {
      float rr[3][PPT + 2];
#pragma unroll
      for (int dy = 0; dy < 3; ++dy) {
        const float* p = &tile[c][ty + dy][txp];
        if (PPT == 4) {
          float4 a4 = *(const float4*)p;        // 16B aligned
          float2 b2 = *(const float2*)(p + 4);  // 8B aligned
          rr[dy][0] = a4.x; rr[dy][1] = a4.y; rr[dy][2] = a4.z; rr[dy][3] = a4.w;
          rr[dy][4] = b2.x; rr[dy][5] = b2.y;
        } else {
          float2 a2 = *(const float2*)p;        // 8B aligned
          float2 b2 = *(const float2*)(p + 2);
          rr[dy][0] = a2.x; rr[dy][1] = a2.y; rr[dy][2] = b2.x; rr[dy][3] = b2.y;
        }
      }
      const int cabs = cc + c;
#pragma unroll
      for (int o = 0; o < COUTG; ++o) {
        const float4* wp = (const float4*)&wsm[(o * CIN + cabs) * 12];
        float4 wa = wp[0];
        float4 wb = wp[1];
        float w8 = wsm[(o * CIN + cabs) * 12 + 8];
#pragma unroll
        for (int i = 0; i < PPT; ++i) {
          float s = acc[o][i];
          s = fmaf(rr[0][i + 0], wa.x, s);
          s = fmaf(rr[0][i + 1], wa.y, s);
          s = fmaf(rr[0][i + 2], wa.z, s);
          s = fmaf(rr[1][i + 0], wa.w, s);
          s = fmaf(rr[1][i + 1], wb.x, s);
          s = fmaf(rr[1][i + 2], wb.y, s);
          s = fmaf(rr[2][i + 0], wb.z, s);
          s = fmaf(rr[2][i + 1], wb.w, s);
          s = fmaf(rr[2][i + 2], w8, s);
          acc[o][i] = s;
        }
      }
    }
  }

  const int oy = gy0 + ty;
  const int ox = gx0 + txp;
  if (FUSE_OUT) {
    float sv[PPT];
#pragma unroll
    for (int i = 0; i < PPT; ++i) sv[i] = bout[0];
#pragma unroll
    for (int o = 0; o < COUTG; ++o) {
      float bo = bf[obase + o], wo = wout[o];
#pragma unroll
      for (int i = 0; i < PPT; ++i) {
        float rr2 = fmaxf(acc[o][i] + bo, 0.f);
        sv[i] = fmaf(rr2, wo, sv[i]);
      }
    }
#pragma unroll
    for (int i = 0; i < PPT; ++i) sv[i] = 1.f / (1.f + __expf(-sv[i]));
    if (PPT == 4) *(float4*)&out[(b * H + oy) * W + ox] = *(float4*)sv;
    else          *(float2*)&out[(b * H + oy) * W + ox] = *(float2*)sv;
  } else {
#pragma unroll
    for (int o = 0; o < COUTG; ++o) {
      float bo = bf[obase + o];
      float rv[PPT];
#pragma unroll
      for (int i = 0; i < PPT; ++i) rv[i] = fmaxf(acc[o][i] + bo, 0.f);
      float* dst = &out[((b * COUT + obase + o) * H + oy) * W + ox];
      if (PPT == 4) *(float4*)dst = *(float4*)rv;
      else          *(float2*)dst = *(float2*)rv;
    }
  }
}

// ---------------------------------------------------------------------------
// FCAS on the 64x64 channel x4[0,1].
// ---------------------------------------------------------------------------
__global__ void fcas_count_kernel(const float* __restrict__ ch,
                                  const float* __restrict__ w,
                                  const float* __restrict__ bb,
                                  float* __restrict__ scratch) {
  const int H = 64, W = 64, N = H * W;
  __shared__ float vals[N];
  for (int i = threadIdx.x; i < N; i += blockDim.x) vals[i] = ch[i];
  __syncthreads();
  int idx = blockIdx.x * blockDim.x + threadIdx.x;
  if (idx >= N) return;
  float v = vals[idx];
  int p = 0, n = 0, e = 0;
  for (int k = 0; k < N; ++k) {
    float u = vals[k];
    p += (u > v);
    n += (u == v);
    e += (u < v);
  }
  float val = ((float)p * w[0] + bb[0] + (float)n * w[1] + bb[1] +
               (float)e * w[2] + bb[2]) / 3.0f;
  int i = idx >> 6, j = idx & 63;
  bool interior = (i >= 1) && (i <= H - 2) && (j >= 1) && (j <= W - 2);
  scratch[idx] = interior ? val : v;
}

__global__ void fcas_copy_kernel(const float* __restrict__ scratch,
                                 float* __restrict__ ch) {
  int i = blockIdx.x * 256 + threadIdx.x;
  if (i < 4096) ch[i] = scratch[i];
}

// ---------------------------------------------------------------------------
extern "C" void kernel_launch(void* const* d_in, const int* in_sizes, int n_in,
                              void* d_out, int out_size, void* d_ws, size_t ws_size,
                              hipStream_t stream) {
  const float* x      = (const float*)d_in[0];
  const float* w_inc  = (const float*)d_in[1];
  const float* b_inc  = (const float*)d_in[2];
  const float* g_inc  = (const float*)d_in[3];
  const float* a_inc  = (const float*)d_in[4];
  const float* w_d1   = (const float*)d_in[5];
  const float* b_d1   = (const float*)d_in[6];
  const float* g_d1   = (const float*)d_in[7];
  const float* a_d1   = (const float*)d_in[8];
  const float* w_d2   = (const float*)d_in[9];
  const float* b_d2   = (const float*)d_in[10];
  const float* g_d2   = (const float*)d_in[11];
  const float* a_d2   = (const float*)d_in[12];
  const float* w_d3   = (const float*)d_in[13];
  const float* b_d3   = (const float*)d_in[14];
  const float* g_d3   = (const float*)d_in[15];
  const float* a_d3   = (const float*)d_in[16];
  const float* w_u2   = (const float*)d_in[17];
  const float* b_u2   = (const float*)d_in[18];
  const float* g_u2   = (const float*)d_in[19];
  const float* a_u2   = (const float*)d_in[20];
  const float* w_u3   = (const float*)d_in[21];
  const float* b_u3   = (const float*)d_in[22];
  const float* g_u3   = (const float*)d_in[23];
  const float* a_u3   = (const float*)d_in[24];
  const float* w_u4   = (const float*)d_in[25];
  const float* b_u4   = (const float*)d_in[26];
  const float* g_u4   = (const float*)d_in[27];
  const float* a_u4   = (const float*)d_in[28];
  const float* w_out  = (const float*)d_in[29];
  const float* b_out  = (const float*)d_in[30];
  const float* fcas_w = (const float*)d_in[31];
  const float* fcas_b = (const float*)d_in[32];

  float* ws = (float*)d_ws;
  float* x1  = ws;                     // 16,777,216
  float* x2  = x1 + 16777216;          //  8,388,608
  float* x3  = x2 + 8388608;           //  4,194,304
  float* x4  = x3 + 4194304;           //  1,048,576
  float* uo2 = x4 + 1048576;           //  2,097,152
  float* uo3 = uo2 + 2097152;          //  4,194,304
  float* fs  = uo3 + 4194304;          //  4,096
  float* wfp = fs + 4096;
  float* wf_inc = wfp;                 // 216
  float* wf_d1  = wf_inc + 216;        // 1152
  float* wf_d2  = wf_d1 + 1152;        // 4608
  float* wf_d3  = wf_d2 + 4608;        // 9216
  float* wf_u2  = wf_d3 + 9216;        // 9216
  float* wf_u3  = wf_u2 + 9216;        // 2304
  float* wf_u4  = wf_u3 + 2304;        // 576
  float* bf_inc = wf_u4 + 576;         // 8
  float* bf_d1  = bf_inc + 8;          // 16
  float* bf_d2  = bf_d1 + 16;          // 32
  float* bf_d3  = bf_d2 + 32;          // 32
  float* bf_u2  = bf_d3 + 32;          // 16
  float* bf_u3  = bf_u2 + 16;          // 8
  float* bf_u4  = bf_u3 + 8;           // 4
  float* outp = (float*)d_out;

  AllP A;
  A.L[0] = {w_inc, b_inc, g_inc, a_inc, wf_inc, bf_inc, 8, 3};
  A.L[1] = {w_d1, b_d1, g_d1, a_d1, wf_d1, bf_d1, 16, 8};
  A.L[2] = {w_d2, b_d2, g_d2, a_d2, wf_d2, bf_d2, 32, 16};
  A.L[3] = {w_d3, b_d3, g_d3, a_d3, wf_d3, bf_d3, 32, 32};
  A.L[4] = {w_u2, b_u2, g_u2, a_u2, wf_u2, bf_u2, 16, 64};
  A.L[5] = {w_u3, b_u3, g_u3, a_u3, wf_u3, bf_u3, 8, 32};
  A.L[6] = {w_u4, b_u4, g_u4, a_u4, wf_u4, bf_u4, 4, 16};
  prefold_kernel<<<dim3(36, 7), dim3(256), 0, stream>>>(A);

  dim3 blk(256);

  // inc: 3->8 @512, TX=64 (2048 blocks)
  conv3x3_cbr<3, 0, 8, 1, 64, 4, false, false, false><<<dim3(8, 32, 8), blk, 0, stream>>>(
      x, nullptr, wf_inc, bf_inc, nullptr, nullptr, x1, 512, 512);
  // d1: pool(x1) -> 8->16 @256, TX=32, CHUNK=8, OSPLIT=2 (2048 blocks)
  conv3x3_cbr<8, 0, 8, 2, 32, 8, true, false, false><<<dim3(8, 16, 16), blk, 0, stream>>>(
      x1, nullptr, wf_d1, bf_d1, nullptr, nullptr, x2, 256, 256);
  // d2: pool(x2) -> 16->32 @128, TX=32, CHUNK=8, OSPLIT=8 (2048 blocks)
  conv3x3_cbr<16, 0, 4, 8, 32, 8, true, false, false><<<dim3(4, 8, 64), blk, 0, stream>>>(
      x2, nullptr, wf_d2, bf_d2, nullptr, nullptr, x3, 128, 128);
  // d3: pool(x3) -> 32->32 @64, TX=32, CHUNK=8, OSPLIT=16 (1024 blocks)
  conv3x3_cbr<32, 0, 2, 16, 32, 8, true, false, false><<<dim3(2, 4, 128), blk, 0, stream>>>(
      x3, nullptr, wf_d3, bf_d3, nullptr, nullptr, x4, 64, 64);
  // FCAS on x4[0,1]
  fcas_count_kernel<<<dim3(16), blk, 0, stream>>>(x4 + 4096, fcas_w, fcas_b, fs);
  fcas_copy_kernel<<<dim3(16), blk, 0, stream>>>(fs, x4 + 4096);
  // u2: cat(x3, up2(x4)) 64->16 @128, TX=32, CHUNK=8, OSPLIT=4 (1024 blocks)
  conv3x3_cbr<32, 32, 4, 4, 32, 8, false, true, false><<<dim3(4, 8, 32), blk, 0, stream>>>(
      x3, x4, wf_u2, bf_u2, nullptr, nullptr, uo2, 128, 128);
  // u3: cat(x2, up2(u2out)) 32->8 @256, TX=32, CHUNK=8, OSPLIT=2 (2048 blocks)
  conv3x3_cbr<16, 16, 4, 2, 32, 8, false, true, false><<<dim3(8, 16, 16), blk, 0, stream>>>(
      x2, uo2, wf_u3, bf_u3, nullptr, nullptr, uo3, 256, 256);
  // u4: cat(x1, up2(u3out)) 16->4 @512, TX=64, fused 1x1+sigmoid (2048 blocks)
  conv3x3_cbr<8, 8, 4, 1, 64, 4, false, true, true><<<dim3(8, 32, 8), blk, 0, stream>>>(
      x1, uo3, wf_u4, bf_u4, w_out, b_out, outp, 512, 512);
}

// Round 9
// 718.020 us; speedup vs baseline: 2.2171x; 1.3931x over previous
//
#include <hip/hip_runtime.h>
#include <hip/hip_bf16.h>

#define BN_RSQ 0.9999950000374997f  // 1/sqrt(1+1e-5)

// ---------------------------------------------------------------------------
// Prefold BN into conv weights: wf = w*g*rsq, bf = b*g*rsq + a.
// ---------------------------------------------------------------------------
struct LayerP {
  const float* w; const float* b; const float* g; const float* a;
  float* wf; float* bf; int cout; int cin;
};
struct AllP { LayerP L[7]; };

__global__ void prefold_kernel(AllP A) {
  LayerP p = A.L[blockIdx.y];
  int n = p.cout * p.cin * 9;
  int i = blockIdx.x * 256 + threadIdx.x;
  if (i < n) {
    int o = i / (p.cin * 9);
    p.wf[i] = p.w[i] * p.g[o] * BN_RSQ;
  }
  if (i < p.cout) p.bf[i] = p.b[i] * p.g[i] * BN_RSQ + p.a[i];
}

// Async global->LDS copy: 64 lanes x 4B, LDS dest = wave-uniform base + lane*4.
__device__ __forceinline__ void async_row_f32(const float* g, float* l) {
  __builtin_amdgcn_global_load_lds(
      (const __attribute__((address_space(1))) void*)g,
      (__attribute__((address_space(3))) void*)l, 4, 0, 0);
}

// ---------------------------------------------------------------------------
// 3x3 SAME conv (+folded BN) + ReLU.
//   Tile: TX x 16 output px per block (256 threads; thread = TX/16 x-px).
//   Staging is ROW-BASED: wave = rows, lane = x; interior needs no x-bounds.
//   Direct-copy channels on TX=64 layers use __builtin_amdgcn_global_load_lds
//   (fire-and-forget, drains once at the barrier). Transform channels (pool /
//   bilinear) use the VALU path with a DYNAMIC-trip loop.
//   HISTORY (do not repeat): r4 cross-barrier reg prefetch -> VGPR 248,
//   regress. r7 explicit load batching BG=9..18 -> VGPR 256 + scratch spills,
//   2.4x regress. r8 BG=2 with #pragma unroll -> compiler hoisted ALL loads,
//   VGPR 256 again. Staging loops MUST stay dynamic-trip; latency hiding
//   comes from TLP (>=4 blocks/CU) + async direct staging.
//   - CIN1 ch from in1 (POOL_IN: 2x2 maxpool on the fly, in1 is [.,.,2H,2W]),
//     CIN2 ch from in2 (UP_IN2: bilinear 2x upsample align_corners=True,
//     in2 is [B,CIN2,H/2,W/2]).
//   - OSPLIT: output-channel split across blocks (blockIdx.z = og*8 + batch).
//   - FUSE_OUT: 1x1 conv + sigmoid epilogue (requires OSPLIT==1).
// ---------------------------------------------------------------------------
template <int CIN1, int CIN2, int COUTG, int OSPLIT, int TX, int CHUNKP,
          bool POOL_IN, bool UP_IN2, bool FUSE_OUT>
__launch_bounds__(256)
__global__ void conv3x3_cbr(const float* __restrict__ in1,
                            const float* __restrict__ in2,
                            const float* __restrict__ wf,
                            const float* __restrict__ bf,
                            const float* __restrict__ wout,
                            const float* __restrict__ bout,
                            float* __restrict__ out, int H, int W) {
  constexpr int CIN = CIN1 + CIN2;
  constexpr int COUT = COUTG * OSPLIT;
  constexpr int PPT = TX / 16;        // px per thread (2 or 4)
  constexpr int CHUNK = (CIN < CHUNKP) ? CIN : CHUNKP;
  constexpr int XT = TX + 2;          // tile x extent
  constexpr int XS = TX + 4;          // tile x stride
  constexpr int YT = 18;              // tile y extent
  constexpr int ROWS = CHUNK * YT;    // rows per chunk
  constexpr int RPW = (TX == 64) ? 1 : 2;  // rows per wave-pass
  constexpr bool ASYNC1 = (TX == 64) && !POOL_IN;  // in1 rows can go async

  __shared__ float tile[CHUNK][YT][XS];
  __shared__ float wsm[COUTG * CIN * 12];

  const int tid = threadIdx.x;
  const int txp = (tid & 15) * PPT;
  const int ty = tid >> 4;
  const int gx0 = blockIdx.x * TX;
  const int gy0 = blockIdx.y * 16;
  const int b = blockIdx.z & 7;
  const int og = blockIdx.z >> 3;
  const int obase = og * COUTG;

  const int lane = tid & 63;
  const int wv = tid >> 6;                         // wave id 0..3
  const int sub = (TX == 64) ? 0 : (lane >> 5);    // row-within-pass
  const int xl = (TX == 64) ? lane : (lane & 31);  // 0..TX-1
  const int ixi = gx0 + xl;                        // interior global x (valid)

  const int Hi = H >> 1, Wi = W >> 1;
  const float syf = UP_IN2 ? (float)(Hi - 1) / (float)(H - 1) : 0.f;

  // hoisted per-lane x-params for the upsample path
  int ux0 = 0, ux1 = 0;
  float uwx = 0.f;
  if (UP_IN2) {
    const float sx = (float)(Wi - 1) / (float)(W - 1);
    float fx = ixi * sx;
    ux0 = (int)fx;
    ux1 = min(ux0 + 1, Wi - 1);
    uwx = fx - (float)ux0;
  }

  // ---- stage ALL folded weights once ----
  for (int idx = tid; idx < COUTG * CIN * 9; idx += 256) {
    int o = idx / (CIN * 9);
    int r = idx - o * (CIN * 9);
    int c = r / 9;
    int t = r - c * 9;
    wsm[(o * CIN + c) * 12 + t] = wf[((obase + o) * CIN + c) * 9 + t];
  }

  float acc[COUTG][PPT];
#pragma unroll
  for (int o = 0; o < COUTG; ++o)
#pragma unroll
    for (int i = 0; i < PPT; ++i) acc[o][i] = 0.f;

  for (int cc = 0; cc < CIN; cc += CHUNK) {
    __syncthreads();
    // ---- interior staging: wave = rows, lane = x (DYNAMIC trip count) ----
    for (int pr = wv; pr * RPW < ROWS; pr += 4) {
      const int row = pr * RPW + sub;
      const int c = row / YT;
      const int yy = row - c * YT;
      const int iy = gy0 + yy - 1;
      const int cg = cc + c;
      const bool dir1 = (CIN2 == 0 || cg < CIN1);
      if (ASYNC1 && dir1) {
        // wave-uniform branch; fire-and-forget 64x4B row copy
        if (iy >= 0 && iy < H) {
          const int cb = b * CIN1 + cg;
          async_row_f32(in1 + (size_t)(cb * H + iy) * W + gx0 + xl,
                        &tile[c][yy][1]);
        } else {
          tile[c][yy][1 + xl] = 0.f;
        }
        continue;
      }
      float v = 0.f;
      if (iy >= 0 && iy < H) {
        if (dir1) {
          const int cb = b * CIN1 + cg;
          if (POOL_IN) {
            const float* p = in1 + (size_t)(cb * 2 * H + 2 * iy) * (2 * W) + 2 * ixi;
            float2 t0 = *(const float2*)p;
            float2 t1 = *(const float2*)(p + 2 * W);
            v = fmaxf(fmaxf(t0.x, t0.y), fmaxf(t1.x, t1.y));
          } else {
            v = in1[(size_t)(cb * H + iy) * W + ixi];
          }
        } else {
          const int cb = b * CIN2 + (cg - CIN1);
          if (UP_IN2) {
            float fy = iy * syf;
            int y0 = (int)fy;
            int y1 = min(y0 + 1, Hi - 1);
            float wy = fy - (float)y0;
            const float* r0p = in2 + (size_t)(cb * Hi + y0) * Wi;
            const float* r1p = in2 + (size_t)(cb * Hi + y1) * Wi;
            float a00 = r0p[ux0], a01 = r0p[ux1];
            float a10 = r1p[ux0], a11 = r1p[ux1];
            float r0 = a00 * (1.f - wy) + a10 * wy;
            float r1 = a01 * (1.f - wy) + a11 * wy;
            v = r0 * (1.f - uwx) + r1 * uwx;
          } else {
            v = in2[(size_t)(cb * H + iy) * W + ixi];
          }
        }
      }
      tile[c][yy][1 + xl] = v;
    }
    // ---- x-halo columns (2 per row) ----
    for (int idx = tid; idx < 2 * ROWS; idx += 256) {
      const int row = idx >> 1;
      const int side = idx & 1;
      const int c = row / YT;
      const int yy = row - c * YT;
      const int iy = gy0 + yy - 1;
      const int ix = side ? (gx0 + TX) : (gx0 - 1);
      const int cg = cc + c;
      float v = 0.f;
      if (iy >= 0 && iy < H && ix >= 0 && ix < W) {
        if (CIN2 == 0 || cg < CIN1) {
          const int cb = b * CIN1 + cg;
          if (POOL_IN) {
            const float* p = in1 + (size_t)(cb * 2 * H + 2 * iy) * (2 * W) + 2 * ix;
            v = fmaxf(fmaxf(p[0], p[1]), fmaxf(p[2 * W], p[2 * W + 1]));
          } else {
            v = in1[(size_t)(cb * H + iy) * W + ix];
          }
        } else if (UP_IN2) {
          const int cb = b * CIN2 + (cg - CIN1);
          const float sx = (float)(Wi - 1) / (float)(W - 1);
          float fy = iy * syf, fx = ix * sx;
          int y0 = (int)fy; int y1 = min(y0 + 1, Hi - 1);
          int x0 = (int)fx; int x1 = min(x0 + 1, Wi - 1);
          float wy = fy - (float)y0, wx = fx - (float)x0;
          const float* p = in2 + (size_t)cb * Hi * Wi;
          float a00 = p[y0 * Wi + x0], a01 = p[y0 * Wi + x1];
          float a10 = p[y1 * Wi + x0], a11 = p[y1 * Wi + x1];
          float r0 = a00 * (1.f - wy) + a10 * wy;
          float r1 = a01 * (1.f - wy) + a11 * wy;
          v = r0 * (1.f - wx) + r1 * wx;
        } else {
          const int cb = b * CIN2 + (cg - CIN1);
          v = in2[(size_t)(cb * H + iy) * W + ix];
        }
      }
      tile[c][yy][side ? (TX + 1) : 0] = v;
    }
    __syncthreads();
    // ---- compute from LDS: vector reads + FMAs ----
#pragma unroll
    for (int c = 0; c < CHUNK; ++c) {
      float rr[3][PPT + 2];
#pragma unroll
      for (int dy = 0; dy < 3; ++dy) {
        const float* p = &tile[c][ty + dy][txp];
        if (PPT == 4) {
          float4 a4 = *(const float4*)p;        // 16B aligned
          float2 b2 = *(const float2*)(p + 4);  // 8B aligned
          rr[dy][0] = a4.x; rr[dy][1] = a4.y; rr[dy][2] = a4.z; rr[dy][3] = a4.w;
          rr[dy][4] = b2.x; rr[dy][5] = b2.y;
        } else {
          float2 a2 = *(const float2*)p;        // 8B aligned
          float2 b2 = *(const float2*)(p + 2);
          rr[dy][0] = a2.x; rr[dy][1] = a2.y; rr[dy][2] = b2.x; rr[dy][3] = b2.y;
        }
      }
      const int cabs = cc + c;
#pragma unroll
      for (int o = 0; o < COUTG; ++o) {
        const float4* wp = (const float4*)&wsm[(o * CIN + cabs) * 12];
        float4 wa = wp[0];
        float4 wb = wp[1];
        float w8 = wsm[(o * CIN + cabs) * 12 + 8];
#pragma unroll
        for (int i = 0; i < PPT; ++i) {
          float s = acc[o][i];
          s = fmaf(rr[0][i + 0], wa.x, s);
          s = fmaf(rr[0][i + 1], wa.y, s);
          s = fmaf(rr[0][i + 2], wa.z, s);
          s = fmaf(rr[1][i + 0], wa.w, s);
          s = fmaf(rr[1][i + 1], wb.x, s);
          s = fmaf(rr[1][i + 2], wb.y, s);
          s = fmaf(rr[2][i + 0], wb.z, s);
          s = fmaf(rr[2][i + 1], wb.w, s);
          s = fmaf(rr[2][i + 2], w8, s);
          acc[o][i] = s;
        }
      }
    }
  }

  const int oy = gy0 + ty;
  const int ox = gx0 + txp;
  if (FUSE_OUT) {
    float sv[PPT];
#pragma unroll
    for (int i = 0; i < PPT; ++i) sv[i] = bout[0];
#pragma unroll
    for (int o = 0; o < COUTG; ++o) {
      float bo = bf[obase + o], wo = wout[o];
#pragma unroll
      for (int i = 0; i < PPT; ++i) {
        float rr2 = fmaxf(acc[o][i] + bo, 0.f);
        sv[i] = fmaf(rr2, wo, sv[i]);
      }
    }
#pragma unroll
    for (int i = 0; i < PPT; ++i) sv[i] = 1.f / (1.f + __expf(-sv[i]));
    if (PPT == 4) *(float4*)&out[(b * H + oy) * W + ox] = *(float4*)sv;
    else          *(float2*)&out[(b * H + oy) * W + ox] = *(float2*)sv;
  } else {
#pragma unroll
    for (int o = 0; o < COUTG; ++o) {
      float bo = bf[obase + o];
      float rv[PPT];
#pragma unroll
      for (int i = 0; i < PPT; ++i) rv[i] = fmaxf(acc[o][i] + bo, 0.f);
      float* dst = &out[((b * COUT + obase + o) * H + oy) * W + ox];
      if (PPT == 4) *(float4*)dst = *(float4*)rv;
      else          *(float2*)dst = *(float2*)rv;
    }
  }
}

// ---------------------------------------------------------------------------
// FCAS on the 64x64 channel x4[0,1].
// ---------------------------------------------------------------------------
__global__ void fcas_count_kernel(const float* __restrict__ ch,
                                  const float* __restrict__ w,
                                  const float* __restrict__ bb,
                                  float* __restrict__ scratch) {
  const int H = 64, W = 64, N = H * W;
  __shared__ float vals[N];
  for (int i = threadIdx.x; i < N; i += blockDim.x) vals[i] = ch[i];
  __syncthreads();
  int idx = blockIdx.x * blockDim.x + threadIdx.x;
  if (idx >= N) return;
  float v = vals[idx];
  int p = 0, n = 0, e = 0;
  for (int k = 0; k < N; ++k) {
    float u = vals[k];
    p += (u > v);
    n += (u == v);
    e += (u < v);
  }
  float val = ((float)p * w[0] + bb[0] + (float)n * w[1] + bb[1] +
               (float)e * w[2] + bb[2]) / 3.0f;
  int i = idx >> 6, j = idx & 63;
  bool interior = (i >= 1) && (i <= H - 2) && (j >= 1) && (j <= W - 2);
  scratch[idx] = interior ? val : v;
}

__global__ void fcas_copy_kernel(const float* __restrict__ scratch,
                                 float* __restrict__ ch) {
  int i = blockIdx.x * 256 + threadIdx.x;
  if (i < 4096) ch[i] = scratch[i];
}

// ---------------------------------------------------------------------------
extern "C" void kernel_launch(void* const* d_in, const int* in_sizes, int n_in,
                              void* d_out, int out_size, void* d_ws, size_t ws_size,
                              hipStream_t stream) {
  const float* x      = (const float*)d_in[0];
  const float* w_inc  = (const float*)d_in[1];
  const float* b_inc  = (const float*)d_in[2];
  const float* g_inc  = (const float*)d_in[3];
  const float* a_inc  = (const float*)d_in[4];
  const float* w_d1   = (const float*)d_in[5];
  const float* b_d1   = (const float*)d_in[6];
  const float* g_d1   = (const float*)d_in[7];
  const float* a_d1   = (const float*)d_in[8];
  const float* w_d2   = (const float*)d_in[9];
  const float* b_d2   = (const float*)d_in[10];
  const float* g_d2   = (const float*)d_in[11];
  const float* a_d2   = (const float*)d_in[12];
  const float* w_d3   = (const float*)d_in[13];
  const float* b_d3   = (const float*)d_in[14];
  const float* g_d3   = (const float*)d_in[15];
  const float* a_d3   = (const float*)d_in[16];
  const float* w_u2   = (const float*)d_in[17];
  const float* b_u2   = (const float*)d_in[18];
  const float* g_u2   = (const float*)d_in[19];
  const float* a_u2   = (const float*)d_in[20];
  const float* w_u3   = (const float*)d_in[21];
  const float* b_u3   = (const float*)d_in[22];
  const float* g_u3   = (const float*)d_in[23];
  const float* a_u3   = (const float*)d_in[24];
  const float* w_u4   = (const float*)d_in[25];
  const float* b_u4   = (const float*)d_in[26];
  const float* g_u4   = (const float*)d_in[27];
  const float* a_u4   = (const float*)d_in[28];
  const float* w_out  = (const float*)d_in[29];
  const float* b_out  = (const float*)d_in[30];
  const float* fcas_w = (const float*)d_in[31];
  const float* fcas_b = (const float*)d_in[32];

  float* ws = (float*)d_ws;
  float* x1  = ws;                     // 16,777,216
  float* x2  = x1 + 16777216;          //  8,388,608
  float* x3  = x2 + 8388608;           //  4,194,304
  float* x4  = x3 + 4194304;           //  1,048,576
  float* uo2 = x4 + 1048576;           //  2,097,152
  float* uo3 = uo2 + 2097152;          //  4,194,304
  float* fs  = uo3 + 4194304;          //  4,096
  float* wfp = fs + 4096;
  float* wf_inc = wfp;                 // 216
  float* wf_d1  = wf_inc + 216;        // 1152
  float* wf_d2  = wf_d1 + 1152;        // 4608
  float* wf_d3  = wf_d2 + 4608;        // 9216
  float* wf_u2  = wf_d3 + 9216;        // 9216
  float* wf_u3  = wf_u2 + 9216;        // 2304
  float* wf_u4  = wf_u3 + 2304;        // 576
  float* bf_inc = wf_u4 + 576;         // 8
  float* bf_d1  = bf_inc + 8;          // 16
  float* bf_d2  = bf_d1 + 16;          // 32
  float* bf_d3  = bf_d2 + 32;          // 32
  float* bf_u2  = bf_d3 + 32;          // 16
  float* bf_u3  = bf_u2 + 16;          // 8
  float* bf_u4  = bf_u3 + 8;           // 4
  float* outp = (float*)d_out;

  AllP A;
  A.L[0] = {w_inc, b_inc, g_inc, a_inc, wf_inc, bf_inc, 8, 3};
  A.L[1] = {w_d1, b_d1, g_d1, a_d1, wf_d1, bf_d1, 16, 8};
  A.L[2] = {w_d2, b_d2, g_d2, a_d2, wf_d2, bf_d2, 32, 16};
  A.L[3] = {w_d3, b_d3, g_d3, a_d3, wf_d3, bf_d3, 32, 32};
  A.L[4] = {w_u2, b_u2, g_u2, a_u2, wf_u2, bf_u2, 16, 64};
  A.L[5] = {w_u3, b_u3, g_u3, a_u3, wf_u3, bf_u3, 8, 32};
  A.L[6] = {w_u4, b_u4, g_u4, a_u4, wf_u4, bf_u4, 4, 16};
  prefold_kernel<<<dim3(36, 7), dim3(256), 0, stream>>>(A);

  dim3 blk(256);

  // inc: 3->8 @512, TX=64, fully async staging (2048 blocks)
  conv3x3_cbr<3, 0, 8, 1, 64, 4, false, false, false><<<dim3(8, 32, 8), blk, 0, stream>>>(
      x, nullptr, wf_inc, bf_inc, nullptr, nullptr, x1, 512, 512);
  // d1: pool(x1) -> 8->16 @256, TX=64, OSPLIT=2 (1024 blocks)
  conv3x3_cbr<8, 0, 8, 2, 64, 4, true, false, false><<<dim3(4, 16, 16), blk, 0, stream>>>(
      x1, nullptr, wf_d1, bf_d1, nullptr, nullptr, x2, 256, 256);
  // d2: pool(x2) -> 16->32 @128, TX=32, CHUNK=8, OSPLIT=8 (2048 blocks)
  conv3x3_cbr<16, 0, 4, 8, 32, 8, true, false, false><<<dim3(4, 8, 64), blk, 0, stream>>>(
      x2, nullptr, wf_d2, bf_d2, nullptr, nullptr, x3, 128, 128);
  // d3: pool(x3) -> 32->32 @64, TX=32, CHUNK=8, OSPLIT=16 (1024 blocks)
  conv3x3_cbr<32, 0, 2, 16, 32, 8, true, false, false><<<dim3(2, 4, 128), blk, 0, stream>>>(
      x3, nullptr, wf_d3, bf_d3, nullptr, nullptr, x4, 64, 64);
  // FCAS on x4[0,1]
  fcas_count_kernel<<<dim3(16), blk, 0, stream>>>(x4 + 4096, fcas_w, fcas_b, fs);
  fcas_copy_kernel<<<dim3(16), blk, 0, stream>>>(fs, x4 + 4096);
  // u2: cat(x3, up2(x4)) 64->16 @128, TX=32, CHUNK=8, OSPLIT=4 (1024 blocks)
  conv3x3_cbr<32, 32, 4, 4, 32, 8, false, true, false><<<dim3(4, 8, 32), blk, 0, stream>>>(
      x3, x4, wf_u2, bf_u2, nullptr, nullptr, uo2, 128, 128);
  // u3: cat(x2, up2(u2out)) 32->8 @256, TX=64, OSPLIT=2 (1024 blocks), CIN1 async
  conv3x3_cbr<16, 16, 4, 2, 64, 4, false, true, false><<<dim3(4, 16, 16), blk, 0, stream>>>(
      x2, uo2, wf_u3, bf_u3, nullptr, nullptr, uo3, 256, 256);
  // u4: cat(x1, up2(u3out)) 16->4 @512, TX=64, fused 1x1+sigmoid, CIN1 async
  conv3x3_cbr<8, 8, 4, 1, 64, 4, false, true, true><<<dim3(8, 32, 8), blk, 0, stream>>>(
      x1, uo3, wf_u4, bf_u4, w_out, b_out, outp, 512, 512);
}

// Round 10
// 640.201 us; speedup vs baseline: 2.4866x; 1.1216x over previous
//
#include <hip/hip_runtime.h>
#include <hip/hip_bf16.h>

#define BN_RSQ 0.9999950000374997f  // 1/sqrt(1+1e-5)

// ---------------------------------------------------------------------------
// Prefold BN into conv weights: wf = w*g*rsq, bf = b*g*rsq + a.
// ---------------------------------------------------------------------------
struct LayerP {
  const float* w; const float* b; const float* g; const float* a;
  float* wf; float* bf; int cout; int cin;
};
struct AllP { LayerP L[7]; };

__global__ void prefold_kernel(AllP A) {
  LayerP p = A.L[blockIdx.y];
  int n = p.cout * p.cin * 9;
  int i = blockIdx.x * 256 + threadIdx.x;
  if (i < n) {
    int o = i / (p.cin * 9);
    p.wf[i] = p.w[i] * p.g[o] * BN_RSQ;
  }
  if (i < p.cout) p.bf[i] = p.b[i] * p.g[i] * BN_RSQ + p.a[i];
}

// Async global->LDS copy: 64 lanes x 4B, LDS dest = wave-uniform base + lane*4.
__device__ __forceinline__ void async_row_f32(const float* g, float* l) {
  __builtin_amdgcn_global_load_lds(
      (const __attribute__((address_space(1))) void*)g,
      (__attribute__((address_space(3))) void*)l, 4, 0, 0);
}

// ---------------------------------------------------------------------------
// Bilinear 2x upsample, align_corners=True (verified r1-r2).
// ---------------------------------------------------------------------------
__global__ void up2_kernel(const float* __restrict__ in, float* __restrict__ out,
                           int Hi, int Wi) {
  const int Ho = 2 * Hi, Wo = 2 * Wi;
  const int ox = blockIdx.x * 16 + threadIdx.x;
  const int oy = blockIdx.y * 16 + threadIdx.y;
  const int bc = blockIdx.z;
  const float sy = (float)(Hi - 1) / (float)(Ho - 1);
  const float sx = (float)(Wi - 1) / (float)(Wo - 1);
  float fy = oy * sy, fx = ox * sx;
  int y0 = (int)floorf(fy); int y1 = min(y0 + 1, Hi - 1);
  int x0 = (int)floorf(fx); int x1 = min(x0 + 1, Wi - 1);
  float wy = fy - (float)y0, wx = fx - (float)x0;
  const float* p = in + (size_t)bc * Hi * Wi;
  float a00 = p[y0 * Wi + x0], a01 = p[y0 * Wi + x1];
  float a10 = p[y1 * Wi + x0], a11 = p[y1 * Wi + x1];
  float r0 = a00 * (1.f - wy) + a10 * wy;
  float r1 = a01 * (1.f - wy) + a11 * wy;
  out[((size_t)bc * Ho + oy) * Wo + ox] = r0 * (1.f - wx) + r1 * wx;
}

// ---------------------------------------------------------------------------
// 3x3 SAME conv (+folded BN) + ReLU.  Tile 64x16 px, 256 threads, 4 px/thread.
//   FULLY-ASYNC staging: direct channels (in1, and in2 when !UP_IN2) use
//   global_load_lds (fire-and-forget, drains once at the barrier — no per-
//   iteration waitcnt serialization). Pool layers now read PRECOMPUTED pooled
//   tensors (pool fused into producer epilogue via WRITE_POOL + shfl_down);
//   u2/u3 read precomputed up2 tensors. Only u4's 8 bilinear channels remain
//   on the VALU path.
//   HISTORY (do not repeat): r4 reg prefetch -> VGPR 248; r7/r8 batched or
//   unrolled staging -> VGPR 256 + scratch spills. Staging loops stay
//   dynamic-trip; latency hiding = async + >=4 blocks/CU TLP.
//   - WRITE_POOL: epilogue also writes 2x2-maxpooled output via __shfl_down
//     cross-row max (pout dims [B,COUT,H/2,W/2]).
//   - FUSE_OUT: 1x1 conv + sigmoid epilogue (OSPLIT==1).
// ---------------------------------------------------------------------------
template <int CIN1, int CIN2, int COUTG, int OSPLIT, bool UP_IN2, bool FUSE_OUT,
          bool WRITE_POOL>
__launch_bounds__(256)
__global__ void conv3x3_cbr(const float* __restrict__ in1,
                            const float* __restrict__ in2,
                            const float* __restrict__ wf,
                            const float* __restrict__ bf,
                            const float* __restrict__ wout,
                            const float* __restrict__ bout,
                            float* __restrict__ out,
                            float* __restrict__ pout, int H, int W) {
  constexpr int CIN = CIN1 + CIN2;
  constexpr int COUT = COUTG * OSPLIT;
  constexpr int PPT = 4;
  constexpr int CHUNK = (CIN < 4) ? CIN : 4;
  constexpr int XS = 68;              // tile x stride (66 used)
  constexpr int YT = 18;              // tile y extent
  constexpr int ROWS = CHUNK * YT;

  __shared__ float tile[CHUNK][YT][XS];
  __shared__ float wsm[COUTG * CIN * 12];

  const int tid = threadIdx.x;
  const int txp = (tid & 15) * PPT;
  const int ty = tid >> 4;
  const int gx0 = blockIdx.x * 64;
  const int gy0 = blockIdx.y * 16;
  const int b = blockIdx.z & 7;
  const int og = blockIdx.z >> 3;
  const int obase = og * COUTG;

  const int lane = tid & 63;
  const int wv = tid >> 6;            // wave id 0..3

  const int Hi = H >> 1, Wi = W >> 1;
  const float syf = UP_IN2 ? (float)(Hi - 1) / (float)(H - 1) : 0.f;

  // hoisted per-lane x-params for the (u4-only) bilinear path
  int ux0 = 0, ux1 = 0;
  float uwx = 0.f;
  if (UP_IN2) {
    const float sx = (float)(Wi - 1) / (float)(W - 1);
    float fx = (gx0 + lane) * sx;
    ux0 = (int)fx;
    ux1 = min(ux0 + 1, Wi - 1);
    uwx = fx - (float)ux0;
  }

  // ---- stage ALL folded weights once ----
  for (int idx = tid; idx < COUTG * CIN * 9; idx += 256) {
    int o = idx / (CIN * 9);
    int r = idx - o * (CIN * 9);
    int c = r / 9;
    int t = r - c * 9;
    wsm[(o * CIN + c) * 12 + t] = wf[((obase + o) * CIN + c) * 9 + t];
  }

  float acc[COUTG][PPT];
#pragma unroll
  for (int o = 0; o < COUTG; ++o)
#pragma unroll
    for (int i = 0; i < PPT; ++i) acc[o][i] = 0.f;

  for (int cc = 0; cc < CIN; cc += CHUNK) {
    __syncthreads();
    // ---- interior rows: wave = row, lane = x (DYNAMIC trip count) ----
    for (int pr = wv; pr < ROWS; pr += 4) {
      const int c = pr / YT;
      const int yy = pr - c * YT;
      const int iy = gy0 + yy - 1;
      const int cg = cc + c;
      const bool dir1 = (CIN2 == 0 || cg < CIN1);
      if (dir1 || !UP_IN2) {
        // direct channel: fire-and-forget async row copy
        const float* src;
        int cb;
        if (dir1) { src = in1; cb = b * CIN1 + cg; }
        else      { src = in2; cb = b * CIN2 + (cg - CIN1); }
        if (iy >= 0 && iy < H) {
          async_row_f32(src + (size_t)(cb * H + iy) * W + gx0 + lane,
                        &tile[c][yy][1]);
        } else {
          tile[c][yy][1 + lane] = 0.f;
        }
      } else {
        // bilinear channel (u4 only)
        float v = 0.f;
        if (iy >= 0 && iy < H) {
          const int cb = b * CIN2 + (cg - CIN1);
          float fy = iy * syf;
          int y0 = (int)fy;
          int y1 = min(y0 + 1, Hi - 1);
          float wy = fy - (float)y0;
          const float* r0p = in2 + (size_t)(cb * Hi + y0) * Wi;
          const float* r1p = in2 + (size_t)(cb * Hi + y1) * Wi;
          float a00 = r0p[ux0], a01 = r0p[ux1];
          float a10 = r1p[ux0], a11 = r1p[ux1];
          float r0 = a00 * (1.f - wy) + a10 * wy;
          float r1 = a01 * (1.f - wy) + a11 * wy;
          v = r0 * (1.f - uwx) + r1 * uwx;
        }
        tile[c][yy][1 + lane] = v;
      }
    }
    // ---- x-halo columns (2 per row) ----
    for (int idx = tid; idx < 2 * ROWS; idx += 256) {
      const int row = idx >> 1;
      const int side = idx & 1;
      const int c = row / YT;
      const int yy = row - c * YT;
      const int iy = gy0 + yy - 1;
      const int ix = side ? (gx0 + 64) : (gx0 - 1);
      const int cg = cc + c;
      float v = 0.f;
      if (iy >= 0 && iy < H && ix >= 0 && ix < W) {
        if (CIN2 == 0 || cg < CIN1) {
          const int cb = b * CIN1 + cg;
          v = in1[(size_t)(cb * H + iy) * W + ix];
        } else if (UP_IN2) {
          const int cb = b * CIN2 + (cg - CIN1);
          const float sx = (float)(Wi - 1) / (float)(W - 1);
          float fy = iy * syf, fx = ix * sx;
          int y0 = (int)fy; int y1 = min(y0 + 1, Hi - 1);
          int x0 = (int)fx; int x1 = min(x0 + 1, Wi - 1);
          float wy = fy - (float)y0, wx = fx - (float)x0;
          const float* p = in2 + (size_t)cb * Hi * Wi;
          float a00 = p[y0 * Wi + x0], a01 = p[y0 * Wi + x1];
          float a10 = p[y1 * Wi + x0], a11 = p[y1 * Wi + x1];
          float r0 = a00 * (1.f - wy) + a10 * wy;
          float r1 = a01 * (1.f - wy) + a11 * wy;
          v = r0 * (1.f - wx) + r1 * wx;
        } else {
          const int cb = b * CIN2 + (cg - CIN1);
          v = in2[(size_t)(cb * H + iy) * W + ix];
        }
      }
      tile[c][yy][side ? 65 : 0] = v;
    }
    __syncthreads();
    // ---- compute from LDS: vector reads + FMAs ----
#pragma unroll
    for (int c = 0; c < CHUNK; ++c) {
      float rr[3][6];
#pragma unroll
      for (int dy = 0; dy < 3; ++dy) {
        const float* p = &tile[c][ty + dy][txp];
        float4 a4 = *(const float4*)p;        // 16B aligned
        float2 b2 = *(const float2*)(p + 4);  // 8B aligned
        rr[dy][0] = a4.x; rr[dy][1] = a4.y; rr[dy][2] = a4.z; rr[dy][3] = a4.w;
        rr[dy][4] = b2.x; rr[dy][5] = b2.y;
      }
      const int cabs = cc + c;
#pragma unroll
      for (int o = 0; o < COUTG; ++o) {
        const float4* wp = (const float4*)&wsm[(o * CIN + cabs) * 12];
        float4 wa = wp[0];
        float4 wb = wp[1];
        float w8 = wsm[(o * CIN + cabs) * 12 + 8];
#pragma unroll
        for (int i = 0; i < PPT; ++i) {
          float s = acc[o][i];
          s = fmaf(rr[0][i + 0], wa.x, s);
          s = fmaf(rr[0][i + 1], wa.y, s);
          s = fmaf(rr[0][i + 2], wa.z, s);
          s = fmaf(rr[1][i + 0], wa.w, s);
          s = fmaf(rr[1][i + 1], wb.x, s);
          s = fmaf(rr[1][i + 2], wb.y, s);
          s = fmaf(rr[2][i + 0], wb.z, s);
          s = fmaf(rr[2][i + 1], wb.w, s);
          s = fmaf(rr[2][i + 2], w8, s);
          acc[o][i] = s;
        }
      }
    }
  }

  const int oy = gy0 + ty;
  const int ox = gx0 + txp;
  if (FUSE_OUT) {
    float sv[PPT];
#pragma unroll
    for (int i = 0; i < PPT; ++i) sv[i] = bout[0];
#pragma unroll
    for (int o = 0; o < COUTG; ++o) {
      float bo = bf[obase + o], wo = wout[o];
#pragma unroll
      for (int i = 0; i < PPT; ++i) {
        float rr2 = fmaxf(acc[o][i] + bo, 0.f);
        sv[i] = fmaf(rr2, wo, sv[i]);
      }
    }
#pragma unroll
    for (int i = 0; i < PPT; ++i) sv[i] = 1.f / (1.f + __expf(-sv[i]));
    *(float4*)&out[((size_t)b * H + oy) * W + ox] = *(float4*)sv;
  } else {
    const int H2 = H >> 1, W2 = W >> 1;
#pragma unroll
    for (int o = 0; o < COUTG; ++o) {
      float bo = bf[obase + o];
      float rv[PPT];
#pragma unroll
      for (int i = 0; i < PPT; ++i) rv[i] = fmaxf(acc[o][i] + bo, 0.f);
      *(float4*)&out[((size_t)(b * COUT + obase + o) * H + oy) * W + ox] =
          *(float4*)rv;
      if (WRITE_POOL) {
        // 2x2 maxpool: x-pairs in-lane, y-pair via shfl (lane+16 = ty+1)
        float m0 = fmaxf(rv[0], rv[1]);
        float m1 = fmaxf(rv[2], rv[3]);
        float q0 = fmaxf(m0, __shfl_down(m0, 16));
        float q1 = fmaxf(m1, __shfl_down(m1, 16));
        if (((lane >> 4) & 1) == 0) {
          float2 pw; pw.x = q0; pw.y = q1;
          *(float2*)&pout[((size_t)(b * COUT + obase + o) * H2 + (oy >> 1)) * W2 +
                          (ox >> 1)] = pw;
        }
      }
    }
  }
}

// ---------------------------------------------------------------------------
// FCAS on the 64x64 channel x4[0,1].
// ---------------------------------------------------------------------------
__global__ void fcas_count_kernel(const float* __restrict__ ch,
                                  const float* __restrict__ w,
                                  const float* __restrict__ bb,
                                  float* __restrict__ scratch) {
  const int H = 64, W = 64, N = H * W;
  __shared__ float vals[N];
  for (int i = threadIdx.x; i < N; i += blockDim.x) vals[i] = ch[i];
  __syncthreads();
  int idx = blockIdx.x * blockDim.x + threadIdx.x;
  if (idx >= N) return;
  float v = vals[idx];
  int p = 0, n = 0, e = 0;
  for (int k = 0; k < N; ++k) {
    float u = vals[k];
    p += (u > v);
    n += (u == v);
    e += (u < v);
  }
  float val = ((float)p * w[0] + bb[0] + (float)n * w[1] + bb[1] +
               (float)e * w[2] + bb[2]) / 3.0f;
  int i = idx >> 6, j = idx & 63;
  bool interior = (i >= 1) && (i <= H - 2) && (j >= 1) && (j <= W - 2);
  scratch[idx] = interior ? val : v;
}

__global__ void fcas_copy_kernel(const float* __restrict__ scratch,
                                 float* __restrict__ ch) {
  int i = blockIdx.x * 256 + threadIdx.x;
  if (i < 4096) ch[i] = scratch[i];
}

// ---------------------------------------------------------------------------
extern "C" void kernel_launch(void* const* d_in, const int* in_sizes, int n_in,
                              void* d_out, int out_size, void* d_ws, size_t ws_size,
                              hipStream_t stream) {
  const float* x      = (const float*)d_in[0];
  const float* w_inc  = (const float*)d_in[1];
  const float* b_inc  = (const float*)d_in[2];
  const float* g_inc  = (const float*)d_in[3];
  const float* a_inc  = (const float*)d_in[4];
  const float* w_d1   = (const float*)d_in[5];
  const float* b_d1   = (const float*)d_in[6];
  const float* g_d1   = (const float*)d_in[7];
  const float* a_d1   = (const float*)d_in[8];
  const float* w_d2   = (const float*)d_in[9];
  const float* b_d2   = (const float*)d_in[10];
  const float* g_d2   = (const float*)d_in[11];
  const float* a_d2   = (const float*)d_in[12];
  const float* w_d3   = (const float*)d_in[13];
  const float* b_d3   = (const float*)d_in[14];
  const float* g_d3   = (const float*)d_in[15];
  const float* a_d3   = (const float*)d_in[16];
  const float* w_u2   = (const float*)d_in[17];
  const float* b_u2   = (const float*)d_in[18];
  const float* g_u2   = (const float*)d_in[19];
  const float* a_u2   = (const float*)d_in[20];
  const float* w_u3   = (const float*)d_in[21];
  const float* b_u3   = (const float*)d_in[22];
  const float* g_u3   = (const float*)d_in[23];
  const float* a_u3   = (const float*)d_in[24];
  const float* w_u4   = (const float*)d_in[25];
  const float* b_u4   = (const float*)d_in[26];
  const float* g_u4   = (const float*)d_in[27];
  const float* a_u4   = (const float*)d_in[28];
  const float* w_out  = (const float*)d_in[29];
  const float* b_out  = (const float*)d_in[30];
  const float* fcas_w = (const float*)d_in[31];
  const float* fcas_b = (const float*)d_in[32];

  float* ws = (float*)d_ws;
  float* x1  = ws;                     // [8,8,512,512]   16,777,216
  float* p1  = x1 + 16777216;          // [8,8,256,256]    4,194,304
  float* x2  = p1 + 4194304;           // [8,16,256,256]   8,388,608
  float* p2  = x2 + 8388608;           // [8,16,128,128]   2,097,152
  float* x3  = p2 + 2097152;           // [8,32,128,128]   4,194,304
  float* p3  = x3 + 4194304;           // [8,32,64,64]     1,048,576
  float* x4  = p3 + 1048576;           // [8,32,64,64]     1,048,576
  float* upa = x4 + 1048576;           // [8,32,128,128]   4,194,304
  float* uo2 = upa + 4194304;          // [8,16,128,128]   2,097,152
  float* uo3 = uo2 + 2097152;          // [8,8,256,256]    4,194,304
  float* fs  = uo3 + 4194304;          // 4,096
  // upb aliases [x3 .. x3+8.4M): x3/p3/x4/upa are all dead once u2 finished,
  // and up2(uo2) runs after u2. uo2 lies beyond the aliased range.
  float* upb = x3;                     // [8,16,256,256]   8,388,608 (alias)
  float* wfp = fs + 4096;
  float* wf_inc = wfp;                 // 216
  float* wf_d1  = wf_inc + 216;        // 1152
  float* wf_d2  = wf_d1 + 1152;        // 4608
  float* wf_d3  = wf_d2 + 4608;        // 9216
  float* wf_u2  = wf_d3 + 9216;        // 9216
  float* wf_u3  = wf_u2 + 9216;        // 2304
  float* wf_u4  = wf_u3 + 2304;        // 576
  float* bf_inc = wf_u4 + 576;         // 8
  float* bf_d1  = bf_inc + 8;          // 16
  float* bf_d2  = bf_d1 + 16;          // 32
  float* bf_d3  = bf_d2 + 32;          // 32
  float* bf_u2  = bf_d3 + 32;          // 16
  float* bf_u3  = bf_u2 + 16;          // 8
  float* bf_u4  = bf_u3 + 8;           // 4
  float* outp = (float*)d_out;

  AllP A;
  A.L[0] = {w_inc, b_inc, g_inc, a_inc, wf_inc, bf_inc, 8, 3};
  A.L[1] = {w_d1, b_d1, g_d1, a_d1, wf_d1, bf_d1, 16, 8};
  A.L[2] = {w_d2, b_d2, g_d2, a_d2, wf_d2, bf_d2, 32, 16};
  A.L[3] = {w_d3, b_d3, g_d3, a_d3, wf_d3, bf_d3, 32, 32};
  A.L[4] = {w_u2, b_u2, g_u2, a_u2, wf_u2, bf_u2, 16, 64};
  A.L[5] = {w_u3, b_u3, g_u3, a_u3, wf_u3, bf_u3, 8, 32};
  A.L[6] = {w_u4, b_u4, g_u4, a_u4, wf_u4, bf_u4, 4, 16};
  prefold_kernel<<<dim3(36, 7), dim3(256), 0, stream>>>(A);

  dim3 blk(256);
  dim3 blk2(16, 16);

  // inc: 3->8 @512, async, writes x1 + pooled p1 (2048 blocks)
  conv3x3_cbr<3, 0, 8, 1, false, false, true><<<dim3(8, 32, 8), blk, 0, stream>>>(
      x, nullptr, wf_inc, bf_inc, nullptr, nullptr, x1, p1, 512, 512);
  // d1: p1 -> 8->16 @256, async, writes x2 + pooled p2 (OS2, 1024 blocks)
  conv3x3_cbr<8, 0, 8, 2, false, false, true><<<dim3(4, 16, 16), blk, 0, stream>>>(
      p1, nullptr, wf_d1, bf_d1, nullptr, nullptr, x2, p2, 256, 256);
  // d2: p2 -> 16->32 @128, async, writes x3 + pooled p3 (OS8, 1024 blocks)
  conv3x3_cbr<16, 0, 4, 8, false, false, true><<<dim3(2, 8, 64), blk, 0, stream>>>(
      p2, nullptr, wf_d2, bf_d2, nullptr, nullptr, x3, p3, 128, 128);
  // d3: p3 -> 32->32 @64, async (OS16, 512 blocks)
  conv3x3_cbr<32, 0, 2, 16, false, false, false><<<dim3(1, 4, 128), blk, 0, stream>>>(
      p3, nullptr, wf_d3, bf_d3, nullptr, nullptr, x4, nullptr, 64, 64);
  // FCAS on x4[0,1]
  fcas_count_kernel<<<dim3(16), blk, 0, stream>>>(x4 + 4096, fcas_w, fcas_b, fs);
  fcas_copy_kernel<<<dim3(16), blk, 0, stream>>>(fs, x4 + 4096);
  // up2(x4): [8,32,64,64] -> upa [8,32,128,128]
  up2_kernel<<<dim3(8, 8, 256), blk2, 0, stream>>>(x4, upa, 64, 64);
  // u2: cat(x3, upa) 64->16 @128, all-async (OS8, 1024 blocks)
  conv3x3_cbr<32, 32, 2, 8, false, false, false><<<dim3(2, 8, 64), blk, 0, stream>>>(
      x3, upa, wf_u2, bf_u2, nullptr, nullptr, uo2, nullptr, 128, 128);
  // up2(uo2): [8,16,128,128] -> upb [8,16,256,256]
  up2_kernel<<<dim3(16, 16, 128), blk2, 0, stream>>>(uo2, upb, 128, 128);
  // u3: cat(x2, upb) 32->8 @256, all-async (OS2, 1024 blocks)
  conv3x3_cbr<16, 16, 4, 2, false, false, false><<<dim3(4, 16, 16), blk, 0, stream>>>(
      x2, upb, wf_u3, bf_u3, nullptr, nullptr, uo3, nullptr, 256, 256);
  // u4: cat(x1, up2(uo3)) 16->4 @512, fused bilinear + 1x1 + sigmoid (2048)
  conv3x3_cbr<8, 8, 4, 1, true, true, false><<<dim3(8, 32, 8), blk, 0, stream>>>(
      x1, uo3, wf_u4, bf_u4, w_out, b_out, outp, nullptr, 512, 512);
}

// Round 11
// 636.763 us; speedup vs baseline: 2.5001x; 1.0054x over previous
//
#include <hip/hip_runtime.h>
#include <hip/hip_bf16.h>

#define BN_RSQ 0.9999950000374997f  // 1/sqrt(1+1e-5)

// ---------------------------------------------------------------------------
// Prefold BN into conv weights: wf = w*g*rsq, bf = b*g*rsq + a.
// ---------------------------------------------------------------------------
struct LayerP {
  const float* w; const float* b; const float* g; const float* a;
  float* wf; float* bf; int cout; int cin;
};
struct AllP { LayerP L[7]; };

__global__ void prefold_kernel(AllP A) {
  LayerP p = A.L[blockIdx.y];
  int n = p.cout * p.cin * 9;
  int i = blockIdx.x * 256 + threadIdx.x;
  if (i < n) {
    int o = i / (p.cin * 9);
    p.wf[i] = p.w[i] * p.g[o] * BN_RSQ;
  }
  if (i < p.cout) p.bf[i] = p.b[i] * p.g[i] * BN_RSQ + p.a[i];
}

// Async global->LDS copy: 64 lanes x 4B, LDS dest = wave-uniform base + lane*4.
__device__ __forceinline__ void async_row_f32(const float* g, float* l) {
  __builtin_amdgcn_global_load_lds(
      (const __attribute__((address_space(1))) void*)g,
      (__attribute__((address_space(3))) void*)l, 4, 0, 0);
}

// ---------------------------------------------------------------------------
// Bilinear 2x upsample, align_corners=True (verified r1-r2).
// ---------------------------------------------------------------------------
__global__ void up2_kernel(const float* __restrict__ in, float* __restrict__ out,
                           int Hi, int Wi) {
  const int Ho = 2 * Hi, Wo = 2 * Wi;
  const int ox = blockIdx.x * 16 + threadIdx.x;
  const int oy = blockIdx.y * 16 + threadIdx.y;
  const int bc = blockIdx.z;
  const float sy = (float)(Hi - 1) / (float)(Ho - 1);
  const float sx = (float)(Wi - 1) / (float)(Wo - 1);
  float fy = oy * sy, fx = ox * sx;
  int y0 = (int)floorf(fy); int y1 = min(y0 + 1, Hi - 1);
  int x0 = (int)floorf(fx); int x1 = min(x0 + 1, Wi - 1);
  float wy = fy - (float)y0, wx = fx - (float)x0;
  const float* p = in + (size_t)bc * Hi * Wi;
  float a00 = p[y0 * Wi + x0], a01 = p[y0 * Wi + x1];
  float a10 = p[y1 * Wi + x0], a11 = p[y1 * Wi + x1];
  float r0 = a00 * (1.f - wy) + a10 * wy;
  float r1 = a01 * (1.f - wy) + a11 * wy;
  out[((size_t)bc * Ho + oy) * Wo + ox] = r0 * (1.f - wx) + r1 * wx;
}

// ---------------------------------------------------------------------------
// 3x3 SAME conv (+folded BN) + ReLU.  Tile 64x16 px, 256 threads, 4 px/thread.
//   Staging: wave = channel (CHUNK<=4 = #waves), loop = row. No per-row
//   division, base address hoisted; direct channels use global_load_lds
//   (fire-and-forget, drains once at the barrier). Only u4's bilinear
//   channels use the VALU path (dynamic #pragma unroll 1 loop — r7/r8: any
//   unrolled VALU-load staging loop lets the compiler hoist all loads ->
//   VGPR 256 + scratch spills).
//   Grid: >=2048 blocks on all big convs (r10: 1024-block layers were
//   grid-limited to 4 blocks/CU, occupancy 33%). Duplicated staging fetch is
//   cheap (HBM at ~6% of peak).
//   - WRITE_POOL: epilogue also writes 2x2-maxpooled output via __shfl_down.
//   - FUSE_OUT: 1x1 conv + sigmoid epilogue (OSPLIT==1).
// ---------------------------------------------------------------------------
template <int CIN1, int CIN2, int COUTG, int OSPLIT, bool UP_IN2, bool FUSE_OUT,
          bool WRITE_POOL>
__launch_bounds__(256)
__global__ void conv3x3_cbr(const float* __restrict__ in1,
                            const float* __restrict__ in2,
                            const float* __restrict__ wf,
                            const float* __restrict__ bf,
                            const float* __restrict__ wout,
                            const float* __restrict__ bout,
                            float* __restrict__ out,
                            float* __restrict__ pout, int H, int W) {
  constexpr int CIN = CIN1 + CIN2;
  constexpr int COUT = COUTG * OSPLIT;
  constexpr int PPT = 4;
  constexpr int CHUNK = (CIN < 4) ? CIN : 4;
  constexpr int XS = 68;              // tile x stride (66 used)
  constexpr int YT = 18;              // tile y extent
  constexpr int ROWS = CHUNK * YT;

  __shared__ float tile[CHUNK][YT][XS];
  __shared__ float wsm[COUTG * CIN * 12];

  const int tid = threadIdx.x;
  const int txp = (tid & 15) * PPT;
  const int ty = tid >> 4;
  const int gx0 = blockIdx.x * 64;
  const int gy0 = blockIdx.y * 16;
  const int b = blockIdx.z & 7;
  const int og = blockIdx.z >> 3;
  const int obase = og * COUTG;

  const int lane = tid & 63;
  const int wv = tid >> 6;            // wave id 0..3

  const int Hi = H >> 1, Wi = W >> 1;
  const float syf = UP_IN2 ? (float)(Hi - 1) / (float)(H - 1) : 0.f;

  // hoisted per-lane x-params for the (u4-only) bilinear path
  int ux0 = 0, ux1 = 0;
  float uwx = 0.f;
  if (UP_IN2) {
    const float sx = (float)(Wi - 1) / (float)(W - 1);
    float fx = (gx0 + lane) * sx;
    ux0 = (int)fx;
    ux1 = min(ux0 + 1, Wi - 1);
    uwx = fx - (float)ux0;
  }

  // ---- stage ALL folded weights once ----
  for (int idx = tid; idx < COUTG * CIN * 9; idx += 256) {
    int o = idx / (CIN * 9);
    int r = idx - o * (CIN * 9);
    int c = r / 9;
    int t = r - c * 9;
    wsm[(o * CIN + c) * 12 + t] = wf[((obase + o) * CIN + c) * 9 + t];
  }

  float acc[COUTG][PPT];
#pragma unroll
  for (int o = 0; o < COUTG; ++o)
#pragma unroll
    for (int i = 0; i < PPT; ++i) acc[o][i] = 0.f;

  for (int cc = 0; cc < CIN; cc += CHUNK) {
    __syncthreads();
    // ---- interior rows: wave = channel, loop = row (no divisions) ----
    if (wv < CHUNK) {
      const int c = wv;
      const int cg = cc + c;
      const bool dir1 = (CIN2 == 0 || cg < CIN1);
      if (dir1 || !UP_IN2) {
        const float* src;
        int cb;
        if (dir1) { src = in1; cb = b * CIN1 + cg; }
        else      { src = in2; cb = b * CIN2 + (cg - CIN1); }
        const float* base =
            src + (size_t)cb * H * W + (size_t)(gy0 - 1) * W + gx0 + lane;
#pragma unroll
        for (int yy = 0; yy < YT; ++yy) {
          const int iy = gy0 + yy - 1;
          if (iy >= 0 && iy < H) {
            async_row_f32(base + (size_t)yy * W, &tile[c][yy][1]);
          } else {
            tile[c][yy][1 + lane] = 0.f;
          }
        }
      } else {
        // bilinear channel (u4 only) — keep dynamic, do NOT unroll (spills)
        const int cb = b * CIN2 + (cg - CIN1);
#pragma unroll 1
        for (int yy = 0; yy < YT; ++yy) {
          const int iy = gy0 + yy - 1;
          float v = 0.f;
          if (iy >= 0 && iy < H) {
            float fy = iy * syf;
            int y0 = (int)fy;
            int y1 = min(y0 + 1, Hi - 1);
            float wy = fy - (float)y0;
            const float* r0p = in2 + (size_t)(cb * Hi + y0) * Wi;
            const float* r1p = in2 + (size_t)(cb * Hi + y1) * Wi;
            float a00 = r0p[ux0], a01 = r0p[ux1];
            float a10 = r1p[ux0], a11 = r1p[ux1];
            float r0 = a00 * (1.f - wy) + a10 * wy;
            float r1 = a01 * (1.f - wy) + a11 * wy;
            v = r0 * (1.f - uwx) + r1 * uwx;
          }
          tile[c][yy][1 + lane] = v;
        }
      }
    }
    // ---- x-halo columns (2 per row) ----
    for (int idx = tid; idx < 2 * ROWS; idx += 256) {
      const int row = idx >> 1;
      const int side = idx & 1;
      const int c = row / YT;
      const int yy = row - c * YT;
      const int iy = gy0 + yy - 1;
      const int ix = side ? (gx0 + 64) : (gx0 - 1);
      const int cg = cc + c;
      float v = 0.f;
      if (iy >= 0 && iy < H && ix >= 0 && ix < W) {
        if (CIN2 == 0 || cg < CIN1) {
          const int cb = b * CIN1 + cg;
          v = in1[(size_t)(cb * H + iy) * W + ix];
        } else if (UP_IN2) {
          const int cb = b * CIN2 + (cg - CIN1);
          const float sx = (float)(Wi - 1) / (float)(W - 1);
          float fy = iy * syf, fx = ix * sx;
          int y0 = (int)fy; int y1 = min(y0 + 1, Hi - 1);
          int x0 = (int)fx; int x1 = min(x0 + 1, Wi - 1);
          float wy = fy - (float)y0, wx = fx - (float)x0;
          const float* p = in2 + (size_t)cb * Hi * Wi;
          float a00 = p[y0 * Wi + x0], a01 = p[y0 * Wi + x1];
          float a10 = p[y1 * Wi + x0], a11 = p[y1 * Wi + x1];
          float r0 = a00 * (1.f - wy) + a10 * wy;
          float r1 = a01 * (1.f - wy) + a11 * wy;
          v = r0 * (1.f - wx) + r1 * wx;
        } else {
          const int cb = b * CIN2 + (cg - CIN1);
          v = in2[(size_t)(cb * H + iy) * W + ix];
        }
      }
      tile[c][yy][side ? 65 : 0] = v;
    }
    __syncthreads();
    // ---- compute from LDS: vector reads + FMAs ----
#pragma unroll
    for (int c = 0; c < CHUNK; ++c) {
      float rr[3][6];
#pragma unroll
      for (int dy = 0; dy < 3; ++dy) {
        const float* p = &tile[c][ty + dy][txp];
        float4 a4 = *(const float4*)p;        // 16B aligned
        float2 b2 = *(const float2*)(p + 4);  // 8B aligned
        rr[dy][0] = a4.x; rr[dy][1] = a4.y; rr[dy][2] = a4.z; rr[dy][3] = a4.w;
        rr[dy][4] = b2.x; rr[dy][5] = b2.y;
      }
      const int cabs = cc + c;
#pragma unroll
      for (int o = 0; o < COUTG; ++o) {
        const float4* wp = (const float4*)&wsm[(o * CIN + cabs) * 12];
        float4 wa = wp[0];
        float4 wb = wp[1];
        float w8 = wsm[(o * CIN + cabs) * 12 + 8];
#pragma unroll
        for (int i = 0; i < PPT; ++i) {
          float s = acc[o][i];
          s = fmaf(rr[0][i + 0], wa.x, s);
          s = fmaf(rr[0][i + 1], wa.y, s);
          s = fmaf(rr[0][i + 2], wa.z, s);
          s = fmaf(rr[1][i + 0], wa.w, s);
          s = fmaf(rr[1][i + 1], wb.x, s);
          s = fmaf(rr[1][i + 2], wb.y, s);
          s = fmaf(rr[2][i + 0], wb.z, s);
          s = fmaf(rr[2][i + 1], wb.w, s);
          s = fmaf(rr[2][i + 2], w8, s);
          acc[o][i] = s;
        }
      }
    }
  }

  const int oy = gy0 + ty;
  const int ox = gx0 + txp;
  if (FUSE_OUT) {
    float sv[PPT];
#pragma unroll
    for (int i = 0; i < PPT; ++i) sv[i] = bout[0];
#pragma unroll
    for (int o = 0; o < COUTG; ++o) {
      float bo = bf[obase + o], wo = wout[o];
#pragma unroll
      for (int i = 0; i < PPT; ++i) {
        float rr2 = fmaxf(acc[o][i] + bo, 0.f);
        sv[i] = fmaf(rr2, wo, sv[i]);
      }
    }
#pragma unroll
    for (int i = 0; i < PPT; ++i) sv[i] = 1.f / (1.f + __expf(-sv[i]));
    *(float4*)&out[((size_t)b * H + oy) * W + ox] = *(float4*)sv;
  } else {
    const int H2 = H >> 1, W2 = W >> 1;
#pragma unroll
    for (int o = 0; o < COUTG; ++o) {
      float bo = bf[obase + o];
      float rv[PPT];
#pragma unroll
      for (int i = 0; i < PPT; ++i) rv[i] = fmaxf(acc[o][i] + bo, 0.f);
      *(float4*)&out[((size_t)(b * COUT + obase + o) * H + oy) * W + ox] =
          *(float4*)rv;
      if (WRITE_POOL) {
        float m0 = fmaxf(rv[0], rv[1]);
        float m1 = fmaxf(rv[2], rv[3]);
        float q0 = fmaxf(m0, __shfl_down(m0, 16));
        float q1 = fmaxf(m1, __shfl_down(m1, 16));
        if (((lane >> 4) & 1) == 0) {
          float2 pw; pw.x = q0; pw.y = q1;
          *(float2*)&pout[((size_t)(b * COUT + obase + o) * H2 + (oy >> 1)) * W2 +
                          (ox >> 1)] = pw;
        }
      }
    }
  }
}

// ---------------------------------------------------------------------------
// FCAS on the 64x64 channel x4[0,1].
// ---------------------------------------------------------------------------
__global__ void fcas_count_kernel(const float* __restrict__ ch,
                                  const float* __restrict__ w,
                                  const float* __restrict__ bb,
                                  float* __restrict__ scratch) {
  const int H = 64, W = 64, N = H * W;
  __shared__ float vals[N];
  for (int i = threadIdx.x; i < N; i += blockDim.x) vals[i] = ch[i];
  __syncthreads();
  int idx = blockIdx.x * blockDim.x + threadIdx.x;
  if (idx >= N) return;
  float v = vals[idx];
  int p = 0, n = 0, e = 0;
  for (int k = 0; k < N; ++k) {
    float u = vals[k];
    p += (u > v);
    n += (u == v);
    e += (u < v);
  }
  float val = ((float)p * w[0] + bb[0] + (float)n * w[1] + bb[1] +
               (float)e * w[2] + bb[2]) / 3.0f;
  int i = idx >> 6, j = idx & 63;
  bool interior = (i >= 1) && (i <= H - 2) && (j >= 1) && (j <= W - 2);
  scratch[idx] = interior ? val : v;
}

__global__ void fcas_copy_kernel(const float* __restrict__ scratch,
                                 float* __restrict__ ch) {
  int i = blockIdx.x * 256 + threadIdx.x;
  if (i < 4096) ch[i] = scratch[i];
}

// ---------------------------------------------------------------------------
extern "C" void kernel_launch(void* const* d_in, const int* in_sizes, int n_in,
                              void* d_out, int out_size, void* d_ws, size_t ws_size,
                              hipStream_t stream) {
  const float* x      = (const float*)d_in[0];
  const float* w_inc  = (const float*)d_in[1];
  const float* b_inc  = (const float*)d_in[2];
  const float* g_inc  = (const float*)d_in[3];
  const float* a_inc  = (const float*)d_in[4];
  const float* w_d1   = (const float*)d_in[5];
  const float* b_d1   = (const float*)d_in[6];
  const float* g_d1   = (const float*)d_in[7];
  const float* a_d1   = (const float*)d_in[8];
  const float* w_d2   = (const float*)d_in[9];
  const float* b_d2   = (const float*)d_in[10];
  const float* g_d2   = (const float*)d_in[11];
  const float* a_d2   = (const float*)d_in[12];
  const float* w_d3   = (const float*)d_in[13];
  const float* b_d3   = (const float*)d_in[14];
  const float* g_d3   = (const float*)d_in[15];
  const float* a_d3   = (const float*)d_in[16];
  const float* w_u2   = (const float*)d_in[17];
  const float* b_u2   = (const float*)d_in[18];
  const float* g_u2   = (const float*)d_in[19];
  const float* a_u2   = (const float*)d_in[20];
  const float* w_u3   = (const float*)d_in[21];
  const float* b_u3   = (const float*)d_in[22];
  const float* g_u3   = (const float*)d_in[23];
  const float* a_u3   = (const float*)d_in[24];
  const float* w_u4   = (const float*)d_in[25];
  const float* b_u4   = (const float*)d_in[26];
  const float* g_u4   = (const float*)d_in[27];
  const float* a_u4   = (const float*)d_in[28];
  const float* w_out  = (const float*)d_in[29];
  const float* b_out  = (const float*)d_in[30];
  const float* fcas_w = (const float*)d_in[31];
  const float* fcas_b = (const float*)d_in[32];

  float* ws = (float*)d_ws;
  float* x1  = ws;                     // [8,8,512,512]   16,777,216
  float* p1  = x1 + 16777216;          // [8,8,256,256]    4,194,304
  float* x2  = p1 + 4194304;           // [8,16,256,256]   8,388,608
  float* p2  = x2 + 8388608;           // [8,16,128,128]   2,097,152
  float* x3  = p2 + 2097152;           // [8,32,128,128]   4,194,304
  float* p3  = x3 + 4194304;           // [8,32,64,64]     1,048,576
  float* x4  = p3 + 1048576;           // [8,32,64,64]     1,048,576
  float* upa = x4 + 1048576;           // [8,32,128,128]   4,194,304
  float* uo2 = upa + 4194304;          // [8,16,128,128]   2,097,152
  float* uo3 = uo2 + 2097152;          // [8,8,256,256]    4,194,304
  float* fs  = uo3 + 4194304;          // 4,096
  // upb aliases [x3 ..): x3/p3/x4/upa are dead once u2 finished; uo2 beyond.
  float* upb = x3;                     // [8,16,256,256]   8,388,608 (alias)
  float* wfp = fs + 4096;
  float* wf_inc = wfp;                 // 216
  float* wf_d1  = wf_inc + 216;        // 1152
  float* wf_d2  = wf_d1 + 1152;        // 4608
  float* wf_d3  = wf_d2 + 4608;        // 9216
  float* wf_u2  = wf_d3 + 9216;        // 9216
  float* wf_u3  = wf_u2 + 9216;        // 2304
  float* wf_u4  = wf_u3 + 2304;        // 576
  float* bf_inc = wf_u4 + 576;         // 8
  float* bf_d1  = bf_inc + 8;          // 16
  float* bf_d2  = bf_d1 + 16;          // 32
  float* bf_d3  = bf_d2 + 32;          // 32
  float* bf_u2  = bf_d3 + 32;          // 16
  float* bf_u3  = bf_u2 + 16;          // 8
  float* bf_u4  = bf_u3 + 8;           // 4
  float* outp = (float*)d_out;

  AllP A;
  A.L[0] = {w_inc, b_inc, g_inc, a_inc, wf_inc, bf_inc, 8, 3};
  A.L[1] = {w_d1, b_d1, g_d1, a_d1, wf_d1, bf_d1, 16, 8};
  A.L[2] = {w_d2, b_d2, g_d2, a_d2, wf_d2, bf_d2, 32, 16};
  A.L[3] = {w_d3, b_d3, g_d3, a_d3, wf_d3, bf_d3, 32, 32};
  A.L[4] = {w_u2, b_u2, g_u2, a_u2, wf_u2, bf_u2, 16, 64};
  A.L[5] = {w_u3, b_u3, g_u3, a_u3, wf_u3, bf_u3, 8, 32};
  A.L[6] = {w_u4, b_u4, g_u4, a_u4, wf_u4, bf_u4, 4, 16};
  prefold_kernel<<<dim3(36, 7), dim3(256), 0, stream>>>(A);

  dim3 blk(256);
  dim3 blk2(16, 16);

  // inc: 3->8 @512, async, writes x1 + pooled p1 (2048 blocks)
  conv3x3_cbr<3, 0, 8, 1, false, false, true><<<dim3(8, 32, 8), blk, 0, stream>>>(
      x, nullptr, wf_inc, bf_inc, nullptr, nullptr, x1, p1, 512, 512);
  // d1: p1 -> 8->16 @256, async, COUTG=4/OS4 (2048 blocks)
  conv3x3_cbr<8, 0, 4, 4, false, false, true><<<dim3(4, 16, 32), blk, 0, stream>>>(
      p1, nullptr, wf_d1, bf_d1, nullptr, nullptr, x2, p2, 256, 256);
  // d2: p2 -> 16->32 @128, async, COUTG=2/OS16 (2048 blocks)
  conv3x3_cbr<16, 0, 2, 16, false, false, true><<<dim3(2, 8, 128), blk, 0, stream>>>(
      p2, nullptr, wf_d2, bf_d2, nullptr, nullptr, x3, p3, 128, 128);
  // d3: p3 -> 32->32 @64, async, COUTG=1/OS32 (1024 blocks)
  conv3x3_cbr<32, 0, 1, 32, false, false, false><<<dim3(1, 4, 256), blk, 0, stream>>>(
      p3, nullptr, wf_d3, bf_d3, nullptr, nullptr, x4, nullptr, 64, 64);
  // FCAS on x4[0,1]
  fcas_count_kernel<<<dim3(16), blk, 0, stream>>>(x4 + 4096, fcas_w, fcas_b, fs);
  fcas_copy_kernel<<<dim3(16), blk, 0, stream>>>(fs, x4 + 4096);
  // up2(x4): [8,32,64,64] -> upa [8,32,128,128]
  up2_kernel<<<dim3(8, 8, 256), blk2, 0, stream>>>(x4, upa, 64, 64);
  // u2: cat(x3, upa) 64->16 @128, all-async, COUTG=1/OS16 (2048 blocks)
  conv3x3_cbr<32, 32, 1, 16, false, false, false><<<dim3(2, 8, 128), blk, 0, stream>>>(
      x3, upa, wf_u2, bf_u2, nullptr, nullptr, uo2, nullptr, 128, 128);
  // up2(uo2): [8,16,128,128] -> upb [8,16,256,256]
  up2_kernel<<<dim3(16, 16, 128), blk2, 0, stream>>>(uo2, upb, 128, 128);
  // u3: cat(x2, upb) 32->8 @256, all-async, COUTG=2/OS4 (2048 blocks)
  conv3x3_cbr<16, 16, 2, 4, false, false, false><<<dim3(4, 16, 32), blk, 0, stream>>>(
      x2, upb, wf_u3, bf_u3, nullptr, nullptr, uo3, nullptr, 256, 256);
  // u4: cat(x1, up2(uo3)) 16->4 @512, fused bilinear + 1x1 + sigmoid (2048)
  conv3x3_cbr<8, 8, 4, 1, true, true, false><<<dim3(8, 32, 8), blk, 0, stream>>>(
      x1, uo3, wf_u4, bf_u4, w_out, b_out, outp, nullptr, 512, 512);
}

// Round 12
// 560.419 us; speedup vs baseline: 2.8406x; 1.1362x over previous
//
#include <hip/hip_runtime.h>
#include <hip/hip_bf16.h>

#define BN_RSQ 0.9999950000374997f  // 1/sqrt(1+1e-5)

// ---------------------------------------------------------------------------
// Prefold BN into conv weights: wf = w*g*rsq, bf = b*g*rsq + a.
// Also zeroes the 16-float zero-row buffer used by the direct conv kernels.
// ---------------------------------------------------------------------------
struct LayerP {
  const float* w; const float* b; const float* g; const float* a;
  float* wf; float* bf; int cout; int cin;
};
struct AllP { LayerP L[7]; float* zbuf; };

__global__ void prefold_kernel(AllP A) {
  LayerP p = A.L[blockIdx.y];
  int n = p.cout * p.cin * 9;
  int i = blockIdx.x * 256 + threadIdx.x;
  if (i < n) {
    int o = i / (p.cin * 9);
    p.wf[i] = p.w[i] * p.g[o] * BN_RSQ;
  }
  if (i < p.cout) p.bf[i] = p.b[i] * p.g[i] * BN_RSQ + p.a[i];
  if (blockIdx.y == 0 && blockIdx.x == 0 && i < 16) A.zbuf[i] = 0.f;
}

// Async global->LDS copy: 64 lanes x 4B, LDS dest = wave-uniform base + lane*4.
__device__ __forceinline__ void async_row_f32(const float* g, float* l) {
  __builtin_amdgcn_global_load_lds(
      (const __attribute__((address_space(1))) void*)g,
      (__attribute__((address_space(3))) void*)l, 4, 0, 0);
}

// ---------------------------------------------------------------------------
// Bilinear 2x upsample, align_corners=True (verified r1-r2).
// ---------------------------------------------------------------------------
__global__ void up2_kernel(const float* __restrict__ in, float* __restrict__ out,
                           int Hi, int Wi) {
  const int Ho = 2 * Hi, Wo = 2 * Wi;
  const int ox = blockIdx.x * 16 + threadIdx.x;
  const int oy = blockIdx.y * 16 + threadIdx.y;
  const int bc = blockIdx.z;
  const float sy = (float)(Hi - 1) / (float)(Ho - 1);
  const float sx = (float)(Wi - 1) / (float)(Wo - 1);
  float fy = oy * sy, fx = ox * sx;
  int y0 = (int)floorf(fy); int y1 = min(y0 + 1, Hi - 1);
  int x0 = (int)floorf(fx); int x1 = min(x0 + 1, Wi - 1);
  float wy = fy - (float)y0, wx = fx - (float)x0;
  const float* p = in + (size_t)bc * Hi * Wi;
  float a00 = p[y0 * Wi + x0], a01 = p[y0 * Wi + x1];
  float a10 = p[y1 * Wi + x0], a11 = p[y1 * Wi + x1];
  float r0 = a00 * (1.f - wy) + a10 * wy;
  float r1 = a01 * (1.f - wy) + a11 * wy;
  out[((size_t)bc * Ho + oy) * Wo + ox] = r0 * (1.f - wx) + r1 * wx;
}

// ---------------------------------------------------------------------------
// DIRECT 3x3 conv (+folded BN) + ReLU — no LDS tile, no per-chunk barriers.
//   Thread = 4 output px (64x16 tile/block). Per channel: 3 rows x
//   (aligned float4 + 2 scalar dwords) straight from global; L1 serves the
//   9x tap reuse (per-channel block footprint 4.7KB << 32KB L1).
//   Borders: OOB rows -> zbuf (16 zeroed floats; zp = zbuf+4-ox makes all
//   lane loads land in zbuf[3..8]); left/right taps zeroed by multiplicative
//   masks selL/selR (loads stay inside d_ws: neighbors of each tensor are
//   other ws tensors — finite values, masked to 0 where logically OOB).
//   Weights broadcast from LDS (single barrier). Channel loops stay
//   `#pragma unroll 1` (r7/r8: unrolled staging loops -> compiler hoists all
//   loads -> VGPR 256 + scratch spills).
//   Rationale (r11): barriered-LDS conv plateaued 5-6x above issue floor;
//   removing the barrier/drain structure is the lever, not retuning it.
// ---------------------------------------------------------------------------
template <int CIN1, int CIN2, int COUTG, int OSPLIT, bool WRITE_POOL>
__launch_bounds__(256)
__global__ void conv3x3_direct(const float* __restrict__ in1,
                               const float* __restrict__ in2,
                               const float* __restrict__ wf,
                               const float* __restrict__ bf,
                               const float* __restrict__ zbuf,
                               float* __restrict__ out,
                               float* __restrict__ pout, int H, int W) {
  constexpr int CIN = CIN1 + CIN2;
  constexpr int COUT = COUTG * OSPLIT;
  __shared__ float wsm[COUTG * CIN * 12];

  const int tid = threadIdx.x;
  const int txp = (tid & 15) * 4;
  const int ty = tid >> 4;
  const int gx0 = blockIdx.x * 64;
  const int gy0 = blockIdx.y * 16;
  const int b = blockIdx.z & 7;
  const int og = blockIdx.z >> 3;
  const int obase = og * COUTG;
  const int lane = tid & 63;

  for (int idx = tid; idx < COUTG * CIN * 9; idx += 256) {
    int o = idx / (CIN * 9);
    int r = idx - o * (CIN * 9);
    int c = r / 9;
    int t = r - c * 9;
    wsm[(o * CIN + c) * 12 + t] = wf[((obase + o) * CIN + c) * 9 + t];
  }
  __syncthreads();

  const int ox = gx0 + txp;
  const int oy = gy0 + ty;
  const bool vM = (oy >= 1);
  const bool vP = (oy + 1 < H);
  const float selL = (ox >= 1) ? 1.f : 0.f;
  const float selR = (ox + 4 < W) ? 1.f : 0.f;
  const float* zp = zbuf + 4 - (size_t)ox;  // lane loads land in zbuf[3..8]

  float acc[COUTG][4];
#pragma unroll
  for (int o = 0; o < COUTG; ++o)
#pragma unroll
    for (int i = 0; i < 4; ++i) acc[o][i] = 0.f;

  auto body = [&](const float* __restrict__ plane, int cabs) {
    const float* rC = plane + (size_t)oy * W;
    const float* rM = vM ? (rC - W) : zp;
    const float* rP = vP ? (rC + W) : zp;
    float rr[3][6];
#pragma unroll
    for (int dy = 0; dy < 3; ++dy) {
      const float* p = (dy == 0 ? rM : (dy == 1 ? rC : rP)) + ox;
      float4 v4 = *(const float4*)p;   // 16B aligned (ox % 4 == 0, W % 4 == 0)
      float lm = p[-1];
      float rp = p[4];
      rr[dy][0] = lm * selL;
      rr[dy][1] = v4.x; rr[dy][2] = v4.y; rr[dy][3] = v4.z; rr[dy][4] = v4.w;
      rr[dy][5] = rp * selR;
    }
#pragma unroll
    for (int o = 0; o < COUTG; ++o) {
      const float4* wp = (const float4*)&wsm[(o * CIN + cabs) * 12];
      float4 wa = wp[0];
      float4 wb = wp[1];
      float w8 = wsm[(o * CIN + cabs) * 12 + 8];
#pragma unroll
      for (int i = 0; i < 4; ++i) {
        float s = acc[o][i];
        s = fmaf(rr[0][i + 0], wa.x, s);
        s = fmaf(rr[0][i + 1], wa.y, s);
        s = fmaf(rr[0][i + 2], wa.z, s);
        s = fmaf(rr[1][i + 0], wa.w, s);
        s = fmaf(rr[1][i + 1], wb.x, s);
        s = fmaf(rr[1][i + 2], wb.y, s);
        s = fmaf(rr[2][i + 0], wb.z, s);
        s = fmaf(rr[2][i + 1], wb.w, s);
        s = fmaf(rr[2][i + 2], w8, s);
        acc[o][i] = s;
      }
    }
  };

#pragma unroll 1
  for (int c = 0; c < CIN1; ++c)
    body(in1 + (size_t)(b * CIN1 + c) * H * W, c);
  if (CIN2 > 0) {
#pragma unroll 1
    for (int c = 0; c < CIN2; ++c)
      body(in2 + (size_t)(b * CIN2 + c) * H * W, CIN1 + c);
  }

  const int H2 = H >> 1, W2 = W >> 1;
#pragma unroll
  for (int o = 0; o < COUTG; ++o) {
    float bo = bf[obase + o];
    float rv[4];
#pragma unroll
    for (int i = 0; i < 4; ++i) rv[i] = fmaxf(acc[o][i] + bo, 0.f);
    *(float4*)&out[((size_t)(b * COUT + obase + o) * H + oy) * W + ox] =
        *(float4*)rv;
    if (WRITE_POOL) {
      float m0 = fmaxf(rv[0], rv[1]);
      float m1 = fmaxf(rv[2], rv[3]);
      float q0 = fmaxf(m0, __shfl_down(m0, 16));
      float q1 = fmaxf(m1, __shfl_down(m1, 16));
      if (((lane >> 4) & 1) == 0) {
        float2 pw; pw.x = q0; pw.y = q1;
        *(float2*)&pout[((size_t)(b * COUT + obase + o) * H2 + (oy >> 1)) * W2 +
                        (ox >> 1)] = pw;
      }
    }
  }
}

// ---------------------------------------------------------------------------
// LDS/async conv (r10/r11 verified) — used only by inc (unguarded harness
// input) and u4 (bilinear in2 + fused 1x1+sigmoid epilogue).
// ---------------------------------------------------------------------------
template <int CIN1, int CIN2, int COUTG, int OSPLIT, bool UP_IN2, bool FUSE_OUT,
          bool WRITE_POOL>
__launch_bounds__(256)
__global__ void conv3x3_cbr(const float* __restrict__ in1,
                            const float* __restrict__ in2,
                            const float* __restrict__ wf,
                            const float* __restrict__ bf,
                            const float* __restrict__ wout,
                            const float* __restrict__ bout,
                            float* __restrict__ out,
                            float* __restrict__ pout, int H, int W) {
  constexpr int CIN = CIN1 + CIN2;
  constexpr int COUT = COUTG * OSPLIT;
  constexpr int PPT = 4;
  constexpr int CHUNK = (CIN < 4) ? CIN : 4;
  constexpr int XS = 68;
  constexpr int YT = 18;
  constexpr int ROWS = CHUNK * YT;

  __shared__ float tile[CHUNK][YT][XS];
  __shared__ float wsm[COUTG * CIN * 12];

  const int tid = threadIdx.x;
  const int txp = (tid & 15) * PPT;
  const int ty = tid >> 4;
  const int gx0 = blockIdx.x * 64;
  const int gy0 = blockIdx.y * 16;
  const int b = blockIdx.z & 7;
  const int og = blockIdx.z >> 3;
  const int obase = og * COUTG;

  const int lane = tid & 63;
  const int wv = tid >> 6;

  const int Hi = H >> 1, Wi = W >> 1;
  const float syf = UP_IN2 ? (float)(Hi - 1) / (float)(H - 1) : 0.f;

  int ux0 = 0, ux1 = 0;
  float uwx = 0.f;
  if (UP_IN2) {
    const float sx = (float)(Wi - 1) / (float)(W - 1);
    float fx = (gx0 + lane) * sx;
    ux0 = (int)fx;
    ux1 = min(ux0 + 1, Wi - 1);
    uwx = fx - (float)ux0;
  }

  for (int idx = tid; idx < COUTG * CIN * 9; idx += 256) {
    int o = idx / (CIN * 9);
    int r = idx - o * (CIN * 9);
    int c = r / 9;
    int t = r - c * 9;
    wsm[(o * CIN + c) * 12 + t] = wf[((obase + o) * CIN + c) * 9 + t];
  }

  float acc[COUTG][PPT];
#pragma unroll
  for (int o = 0; o < COUTG; ++o)
#pragma unroll
    for (int i = 0; i < PPT; ++i) acc[o][i] = 0.f;

  for (int cc = 0; cc < CIN; cc += CHUNK) {
    __syncthreads();
    if (wv < CHUNK) {
      const int c = wv;
      const int cg = cc + c;
      const bool dir1 = (CIN2 == 0 || cg < CIN1);
      if (dir1 || !UP_IN2) {
        const float* src;
        int cb;
        if (dir1) { src = in1; cb = b * CIN1 + cg; }
        else      { src = in2; cb = b * CIN2 + (cg - CIN1); }
        const float* base =
            src + (size_t)cb * H * W + (size_t)(gy0 - 1) * W + gx0 + lane;
#pragma unroll
        for (int yy = 0; yy < YT; ++yy) {
          const int iy = gy0 + yy - 1;
          if (iy >= 0 && iy < H) {
            async_row_f32(base + (size_t)yy * W, &tile[c][yy][1]);
          } else {
            tile[c][yy][1 + lane] = 0.f;
          }
        }
      } else {
        const int cb = b * CIN2 + (cg - CIN1);
#pragma unroll 1
        for (int yy = 0; yy < YT; ++yy) {
          const int iy = gy0 + yy - 1;
          float v = 0.f;
          if (iy >= 0 && iy < H) {
            float fy = iy * syf;
            int y0 = (int)fy;
            int y1 = min(y0 + 1, Hi - 1);
            float wy = fy - (float)y0;
            const float* r0p = in2 + (size_t)(cb * Hi + y0) * Wi;
            const float* r1p = in2 + (size_t)(cb * Hi + y1) * Wi;
            float a00 = r0p[ux0], a01 = r0p[ux1];
            float a10 = r1p[ux0], a11 = r1p[ux1];
            float r0 = a00 * (1.f - wy) + a10 * wy;
            float r1 = a01 * (1.f - wy) + a11 * wy;
            v = r0 * (1.f - uwx) + r1 * uwx;
          }
          tile[c][yy][1 + lane] = v;
        }
      }
    }
    for (int idx = tid; idx < 2 * ROWS; idx += 256) {
      const int row = idx >> 1;
      const int side = idx & 1;
      const int c = row / YT;
      const int yy = row - c * YT;
      const int iy = gy0 + yy - 1;
      const int ix = side ? (gx0 + 64) : (gx0 - 1);
      const int cg = cc + c;
      float v = 0.f;
      if (iy >= 0 && iy < H && ix >= 0 && ix < W) {
        if (CIN2 == 0 || cg < CIN1) {
          const int cb = b * CIN1 + cg;
          v = in1[(size_t)(cb * H + iy) * W + ix];
        } else if (UP_IN2) {
          const int cb = b * CIN2 + (cg - CIN1);
          const float sx = (float)(Wi - 1) / (float)(W - 1);
          float fy = iy * syf, fx = ix * sx;
          int y0 = (int)fy; int y1 = min(y0 + 1, Hi - 1);
          int x0 = (int)fx; int x1 = min(x0 + 1, Wi - 1);
          float wy = fy - (float)y0, wx = fx - (float)x0;
          const float* p = in2 + (size_t)cb * Hi * Wi;
          float a00 = p[y0 * Wi + x0], a01 = p[y0 * Wi + x1];
          float a10 = p[y1 * Wi + x0], a11 = p[y1 * Wi + x1];
          float r0 = a00 * (1.f - wy) + a10 * wy;
          float r1 = a01 * (1.f - wy) + a11 * wy;
          v = r0 * (1.f - wx) + r1 * wx;
        } else {
          const int cb = b * CIN2 + (cg - CIN1);
          v = in2[(size_t)(cb * H + iy) * W + ix];
        }
      }
      tile[c][yy][side ? 65 : 0] = v;
    }
    __syncthreads();
#pragma unroll
    for (int c = 0; c < CHUNK; ++c) {
      float rr[3][6];
#pragma unroll
      for (int dy = 0; dy < 3; ++dy) {
        const float* p = &tile[c][ty + dy][txp];
        float4 a4 = *(const float4*)p;
        float2 b2 = *(const float2*)(p + 4);
        rr[dy][0] = a4.x; rr[dy][1] = a4.y; rr[dy][2] = a4.z; rr[dy][3] = a4.w;
        rr[dy][4] = b2.x; rr[dy][5] = b2.y;
      }
      const int cabs = cc + c;
#pragma unroll
      for (int o = 0; o < COUTG; ++o) {
        const float4* wp = (const float4*)&wsm[(o * CIN + cabs) * 12];
        float4 wa = wp[0];
        float4 wb = wp[1];
        float w8 = wsm[(o * CIN + cabs) * 12 + 8];
#pragma unroll
        for (int i = 0; i < PPT; ++i) {
          float s = acc[o][i];
          s = fmaf(rr[0][i + 0], wa.x, s);
          s = fmaf(rr[0][i + 1], wa.y, s);
          s = fmaf(rr[0][i + 2], wa.z, s);
          s = fmaf(rr[1][i + 0], wa.w, s);
          s = fmaf(rr[1][i + 1], wb.x, s);
          s = fmaf(rr[1][i + 2], wb.y, s);
          s = fmaf(rr[2][i + 0], wb.z, s);
          s = fmaf(rr[2][i + 1], wb.w, s);
          s = fmaf(rr[2][i + 2], w8, s);
          acc[o][i] = s;
        }
      }
    }
  }

  const int oy = gy0 + ty;
  const int ox = gx0 + txp;
  if (FUSE_OUT) {
    float sv[PPT];
#pragma unroll
    for (int i = 0; i < PPT; ++i) sv[i] = bout[0];
#pragma unroll
    for (int o = 0; o < COUTG; ++o) {
      float bo = bf[obase + o], wo = wout[o];
#pragma unroll
      for (int i = 0; i < PPT; ++i) {
        float rr2 = fmaxf(acc[o][i] + bo, 0.f);
        sv[i] = fmaf(rr2, wo, sv[i]);
      }
    }
#pragma unroll
    for (int i = 0; i < PPT; ++i) sv[i] = 1.f / (1.f + __expf(-sv[i]));
    *(float4*)&out[((size_t)b * H + oy) * W + ox] = *(float4*)sv;
  } else {
    const int H2 = H >> 1, W2 = W >> 1;
#pragma unroll
    for (int o = 0; o < COUTG; ++o) {
      float bo = bf[obase + o];
      float rv[PPT];
#pragma unroll
      for (int i = 0; i < PPT; ++i) rv[i] = fmaxf(acc[o][i] + bo, 0.f);
      *(float4*)&out[((size_t)(b * COUT + obase + o) * H + oy) * W + ox] =
          *(float4*)rv;
      if (WRITE_POOL) {
        float m0 = fmaxf(rv[0], rv[1]);
        float m1 = fmaxf(rv[2], rv[3]);
        float q0 = fmaxf(m0, __shfl_down(m0, 16));
        float q1 = fmaxf(m1, __shfl_down(m1, 16));
        if (((lane >> 4) & 1) == 0) {
          float2 pw; pw.x = q0; pw.y = q1;
          *(float2*)&pout[((size_t)(b * COUT + obase + o) * H2 + (oy >> 1)) * W2 +
                          (ox >> 1)] = pw;
        }
      }
    }
  }
}

// ---------------------------------------------------------------------------
// FCAS on the 64x64 channel x4[0,1].
// ---------------------------------------------------------------------------
__global__ void fcas_count_kernel(const float* __restrict__ ch,
                                  const float* __restrict__ w,
                                  const float* __restrict__ bb,
                                  float* __restrict__ scratch) {
  const int H = 64, W = 64, N = H * W;
  __shared__ float vals[N];
  for (int i = threadIdx.x; i < N; i += blockDim.x) vals[i] = ch[i];
  __syncthreads();
  int idx = blockIdx.x * blockDim.x + threadIdx.x;
  if (idx >= N) return;
  float v = vals[idx];
  int p = 0, n = 0, e = 0;
  for (int k = 0; k < N; ++k) {
    float u = vals[k];
    p += (u > v);
    n += (u == v);
    e += (u < v);
  }
  float val = ((float)p * w[0] + bb[0] + (float)n * w[1] + bb[1] +
               (float)e * w[2] + bb[2]) / 3.0f;
  int i = idx >> 6, j = idx & 63;
  bool interior = (i >= 1) && (i <= H - 2) && (j >= 1) && (j <= W - 2);
  scratch[idx] = interior ? val : v;
}

__global__ void fcas_copy_kernel(const float* __restrict__ scratch,
                                 float* __restrict__ ch) {
  int i = blockIdx.x * 256 + threadIdx.x;
  if (i < 4096) ch[i] = scratch[i];
}

// ---------------------------------------------------------------------------
extern "C" void kernel_launch(void* const* d_in, const int* in_sizes, int n_in,
                              void* d_out, int out_size, void* d_ws, size_t ws_size,
                              hipStream_t stream) {
  const float* x      = (const float*)d_in[0];
  const float* w_inc  = (const float*)d_in[1];
  const float* b_inc  = (const float*)d_in[2];
  const float* g_inc  = (const float*)d_in[3];
  const float* a_inc  = (const float*)d_in[4];
  const float* w_d1   = (const float*)d_in[5];
  const float* b_d1   = (const float*)d_in[6];
  const float* g_d1   = (const float*)d_in[7];
  const float* a_d1   = (const float*)d_in[8];
  const float* w_d2   = (const float*)d_in[9];
  const float* b_d2   = (const float*)d_in[10];
  const float* g_d2   = (const float*)d_in[11];
  const float* a_d2   = (const float*)d_in[12];
  const float* w_d3   = (const float*)d_in[13];
  const float* b_d3   = (const float*)d_in[14];
  const float* g_d3   = (const float*)d_in[15];
  const float* a_d3   = (const float*)d_in[16];
  const float* w_u2   = (const float*)d_in[17];
  const float* b_u2   = (const float*)d_in[18];
  const float* g_u2   = (const float*)d_in[19];
  const float* a_u2   = (const float*)d_in[20];
  const float* w_u3   = (const float*)d_in[21];
  const float* b_u3   = (const float*)d_in[22];
  const float* g_u3   = (const float*)d_in[23];
  const float* a_u3   = (const float*)d_in[24];
  const float* w_u4   = (const float*)d_in[25];
  const float* b_u4   = (const float*)d_in[26];
  const float* g_u4   = (const float*)d_in[27];
  const float* a_u4   = (const float*)d_in[28];
  const float* w_out  = (const float*)d_in[29];
  const float* b_out  = (const float*)d_in[30];
  const float* fcas_w = (const float*)d_in[31];
  const float* fcas_b = (const float*)d_in[32];

  float* ws = (float*)d_ws;
  float* x1  = ws;                     // [8,8,512,512]   16,777,216
  float* p1  = x1 + 16777216;          // [8,8,256,256]    4,194,304
  float* x2  = p1 + 4194304;           // [8,16,256,256]   8,388,608
  float* p2  = x2 + 8388608;           // [8,16,128,128]   2,097,152
  float* x3  = p2 + 2097152;           // [8,32,128,128]   4,194,304
  float* p3  = x3 + 4194304;           // [8,32,64,64]     1,048,576
  float* x4  = p3 + 1048576;           // [8,32,64,64]     1,048,576
  float* upa = x4 + 1048576;           // [8,32,128,128]   4,194,304
  float* uo2 = upa + 4194304;          // [8,16,128,128]   2,097,152
  float* uo3 = uo2 + 2097152;          // [8,8,256,256]    4,194,304
  float* fs  = uo3 + 4194304;          // 4,096
  // upb aliases [x3 ..): x3/p3/x4/upa are dead once u2 finished; uo2 beyond.
  float* upb = x3;                     // [8,16,256,256]   8,388,608 (alias)
  float* wfp = fs + 4096;
  float* wf_inc = wfp;                 // 216
  float* wf_d1  = wf_inc + 216;        // 1152
  float* wf_d2  = wf_d1 + 1152;        // 4608
  float* wf_d3  = wf_d2 + 4608;        // 9216
  float* wf_u2  = wf_d3 + 9216;        // 9216
  float* wf_u3  = wf_u2 + 9216;        // 2304
  float* wf_u4  = wf_u3 + 2304;        // 576
  float* bf_inc = wf_u4 + 576;         // 8
  float* bf_d1  = bf_inc + 8;          // 16
  float* bf_d2  = bf_d1 + 16;          // 32
  float* bf_d3  = bf_d2 + 32;          // 32
  float* bf_u2  = bf_d3 + 32;          // 16
  float* bf_u3  = bf_u2 + 16;          // 8
  float* bf_u4  = bf_u3 + 8;           // 4
  float* zbuf   = bf_u4 + 4;           // 16 (16B-aligned)
  float* outp = (float*)d_out;

  AllP A;
  A.L[0] = {w_inc, b_inc, g_inc, a_inc, wf_inc, bf_inc, 8, 3};
  A.L[1] = {w_d1, b_d1, g_d1, a_d1, wf_d1, bf_d1, 16, 8};
  A.L[2] = {w_d2, b_d2, g_d2, a_d2, wf_d2, bf_d2, 32, 16};
  A.L[3] = {w_d3, b_d3, g_d3, a_d3, wf_d3, bf_d3, 32, 32};
  A.L[4] = {w_u2, b_u2, g_u2, a_u2, wf_u2, bf_u2, 16, 64};
  A.L[5] = {w_u3, b_u3, g_u3, a_u3, wf_u3, bf_u3, 8, 32};
  A.L[6] = {w_u4, b_u4, g_u4, a_u4, wf_u4, bf_u4, 4, 16};
  A.zbuf = zbuf;
  prefold_kernel<<<dim3(36, 7), dim3(256), 0, stream>>>(A);

  dim3 blk(256);
  dim3 blk2(16, 16);

  // inc: 3->8 @512, LDS/async kernel (harness input: no guard bytes), +pool
  conv3x3_cbr<3, 0, 8, 1, false, false, true><<<dim3(8, 32, 8), blk, 0, stream>>>(
      x, nullptr, wf_inc, bf_inc, nullptr, nullptr, x1, p1, 512, 512);
  // d1: p1 -> 8->16 @256, DIRECT, COUTG=4/OS4 (2048 blocks), +pool
  conv3x3_direct<8, 0, 4, 4, true><<<dim3(4, 16, 32), blk, 0, stream>>>(
      p1, nullptr, wf_d1, bf_d1, zbuf, x2, p2, 256, 256);
  // d2: p2 -> 16->32 @128, DIRECT, COUTG=4/OS8 (1024 blocks), +pool
  conv3x3_direct<16, 0, 4, 8, true><<<dim3(2, 8, 64), blk, 0, stream>>>(
      p2, nullptr, wf_d2, bf_d2, zbuf, x3, p3, 128, 128);
  // d3: p3 -> 32->32 @64, DIRECT, COUTG=2/OS16 (512 blocks)
  conv3x3_direct<32, 0, 2, 16, false><<<dim3(1, 4, 128), blk, 0, stream>>>(
      p3, nullptr, wf_d3, bf_d3, zbuf, x4, nullptr, 64, 64);
  // FCAS on x4[0,1]
  fcas_count_kernel<<<dim3(16), blk, 0, stream>>>(x4 + 4096, fcas_w, fcas_b, fs);
  fcas_copy_kernel<<<dim3(16), blk, 0, stream>>>(fs, x4 + 4096);
  // up2(x4): [8,32,64,64] -> upa [8,32,128,128]
  up2_kernel<<<dim3(8, 8, 256), blk2, 0, stream>>>(x4, upa, 64, 64);
  // u2: cat(x3, upa) 64->16 @128, DIRECT, COUTG=2/OS8 (1024 blocks)
  conv3x3_direct<32, 32, 2, 8, false><<<dim3(2, 8, 64), blk, 0, stream>>>(
      x3, upa, wf_u2, bf_u2, zbuf, uo2, nullptr, 128, 128);
  // up2(uo2): [8,16,128,128] -> upb [8,16,256,256]
  up2_kernel<<<dim3(16, 16, 128), blk2, 0, stream>>>(uo2, upb, 128, 128);
  // u3: cat(x2, upb) 32->8 @256, DIRECT, COUTG=2/OS4 (2048 blocks)
  conv3x3_direct<16, 16, 2, 4, false><<<dim3(4, 16, 32), blk, 0, stream>>>(
      x2, upb, wf_u3, bf_u3, zbuf, uo3, nullptr, 256, 256);
  // u4: cat(x1, up2(uo3)) 16->4 @512, LDS kernel, fused bilinear+1x1+sigmoid
  conv3x3_cbr<8, 8, 4, 1, true, true, false><<<dim3(8, 32, 8), blk, 0, stream>>>(
      x1, uo3, wf_u4, bf_u4, w_out, b_out, outp, nullptr, 512, 512);
}

// Round 13
// 493.015 us; speedup vs baseline: 3.2290x; 1.1367x over previous
//
#include <hip/hip_runtime.h>
#include <hip/hip_bf16.h>

#define BN_RSQ 0.9999950000374997f  // 1/sqrt(1+1e-5)

// ---------------------------------------------------------------------------
// Prefold BN into conv weights: wf = w*g*rsq, bf = b*g*rsq + a.
// Also zeroes the 16-float zero-row buffer used by the direct conv kernels.
// ---------------------------------------------------------------------------
struct LayerP {
  const float* w; const float* b; const float* g; const float* a;
  float* wf; float* bf; int cout; int cin;
};
struct AllP { LayerP L[7]; float* zbuf; };

__global__ void prefold_kernel(AllP A) {
  LayerP p = A.L[blockIdx.y];
  int n = p.cout * p.cin * 9;
  int i = blockIdx.x * 256 + threadIdx.x;
  if (i < n) {
    int o = i / (p.cin * 9);
    p.wf[i] = p.w[i] * p.g[o] * BN_RSQ;
  }
  if (i < p.cout) p.bf[i] = p.b[i] * p.g[i] * BN_RSQ + p.a[i];
  if (blockIdx.y == 0 && blockIdx.x == 0 && i < 16) A.zbuf[i] = 0.f;
}

// Async global->LDS copy: 64 lanes x 4B, LDS dest = wave-uniform base + lane*4.
__device__ __forceinline__ void async_row_f32(const float* g, float* l) {
  __builtin_amdgcn_global_load_lds(
      (const __attribute__((address_space(1))) void*)g,
      (__attribute__((address_space(3))) void*)l, 4, 0, 0);
}

// ---------------------------------------------------------------------------
// Bilinear 2x upsample, align_corners=True (verified r1-r2).
// ---------------------------------------------------------------------------
__global__ void up2_kernel(const float* __restrict__ in, float* __restrict__ out,
                           int Hi, int Wi) {
  const int Ho = 2 * Hi, Wo = 2 * Wi;
  const int ox = blockIdx.x * 16 + threadIdx.x;
  const int oy = blockIdx.y * 16 + threadIdx.y;
  const int bc = blockIdx.z;
  const float sy = (float)(Hi - 1) / (float)(Ho - 1);
  const float sx = (float)(Wi - 1) / (float)(Wo - 1);
  float fy = oy * sy, fx = ox * sx;
  int y0 = (int)floorf(fy); int y1 = min(y0 + 1, Hi - 1);
  int x0 = (int)floorf(fx); int x1 = min(x0 + 1, Wi - 1);
  float wy = fy - (float)y0, wx = fx - (float)x0;
  const float* p = in + (size_t)bc * Hi * Wi;
  float a00 = p[y0 * Wi + x0], a01 = p[y0 * Wi + x1];
  float a10 = p[y1 * Wi + x0], a11 = p[y1 * Wi + x1];
  float r0 = a00 * (1.f - wy) + a10 * wy;
  float r1 = a01 * (1.f - wy) + a11 * wy;
  out[((size_t)bc * Ho + oy) * Wo + ox] = r0 * (1.f - wx) + r1 * wx;
}

// ---------------------------------------------------------------------------
// DIRECT 3x3 conv (+folded BN) + ReLU — no LDS tile, no per-chunk barriers.
//   (r12 verified: beat the barriered-LDS structure.)
// ---------------------------------------------------------------------------
template <int CIN1, int CIN2, int COUTG, int OSPLIT, bool WRITE_POOL>
__launch_bounds__(256)
__global__ void conv3x3_direct(const float* __restrict__ in1,
                               const float* __restrict__ in2,
                               const float* __restrict__ wf,
                               const float* __restrict__ bf,
                               const float* __restrict__ zbuf,
                               float* __restrict__ out,
                               float* __restrict__ pout, int H, int W) {
  constexpr int CIN = CIN1 + CIN2;
  constexpr int COUT = COUTG * OSPLIT;
  __shared__ float wsm[COUTG * CIN * 12];

  const int tid = threadIdx.x;
  const int txp = (tid & 15) * 4;
  const int ty = tid >> 4;
  const int gx0 = blockIdx.x * 64;
  const int gy0 = blockIdx.y * 16;
  const int b = blockIdx.z & 7;
  const int og = blockIdx.z >> 3;
  const int obase = og * COUTG;
  const int lane = tid & 63;

  for (int idx = tid; idx < COUTG * CIN * 9; idx += 256) {
    int o = idx / (CIN * 9);
    int r = idx - o * (CIN * 9);
    int c = r / 9;
    int t = r - c * 9;
    wsm[(o * CIN + c) * 12 + t] = wf[((obase + o) * CIN + c) * 9 + t];
  }
  __syncthreads();

  const int ox = gx0 + txp;
  const int oy = gy0 + ty;
  const bool vM = (oy >= 1);
  const bool vP = (oy + 1 < H);
  const float selL = (ox >= 1) ? 1.f : 0.f;
  const float selR = (ox + 4 < W) ? 1.f : 0.f;
  const float* zp = zbuf + 4 - (size_t)ox;  // lane loads land in zbuf[3..8]

  float acc[COUTG][4];
#pragma unroll
  for (int o = 0; o < COUTG; ++o)
#pragma unroll
    for (int i = 0; i < 4; ++i) acc[o][i] = 0.f;

  auto body = [&](const float* __restrict__ plane, int cabs) {
    const float* rC = plane + (size_t)oy * W;
    const float* rM = vM ? (rC - W) : zp;
    const float* rP = vP ? (rC + W) : zp;
    float rr[3][6];
#pragma unroll
    for (int dy = 0; dy < 3; ++dy) {
      const float* p = (dy == 0 ? rM : (dy == 1 ? rC : rP)) + ox;
      float4 v4 = *(const float4*)p;   // 16B aligned (ox % 4 == 0, W % 4 == 0)
      float lm = p[-1];
      float rp = p[4];
      rr[dy][0] = lm * selL;
      rr[dy][1] = v4.x; rr[dy][2] = v4.y; rr[dy][3] = v4.z; rr[dy][4] = v4.w;
      rr[dy][5] = rp * selR;
    }
#pragma unroll
    for (int o = 0; o < COUTG; ++o) {
      const float4* wp = (const float4*)&wsm[(o * CIN + cabs) * 12];
      float4 wa = wp[0];
      float4 wb = wp[1];
      float w8 = wsm[(o * CIN + cabs) * 12 + 8];
#pragma unroll
      for (int i = 0; i < 4; ++i) {
        float s = acc[o][i];
        s = fmaf(rr[0][i + 0], wa.x, s);
        s = fmaf(rr[0][i + 1], wa.y, s);
        s = fmaf(rr[0][i + 2], wa.z, s);
        s = fmaf(rr[1][i + 0], wa.w, s);
        s = fmaf(rr[1][i + 1], wb.x, s);
        s = fmaf(rr[1][i + 2], wb.y, s);
        s = fmaf(rr[2][i + 0], wb.z, s);
        s = fmaf(rr[2][i + 1], wb.w, s);
        s = fmaf(rr[2][i + 2], w8, s);
        acc[o][i] = s;
      }
    }
  };

#pragma unroll 1
  for (int c = 0; c < CIN1; ++c)
    body(in1 + (size_t)(b * CIN1 + c) * H * W, c);
  if (CIN2 > 0) {
#pragma unroll 1
    for (int c = 0; c < CIN2; ++c)
      body(in2 + (size_t)(b * CIN2 + c) * H * W, CIN1 + c);
  }

  const int H2 = H >> 1, W2 = W >> 1;
#pragma unroll
  for (int o = 0; o < COUTG; ++o) {
    float bo = bf[obase + o];
    float rv[4];
#pragma unroll
    for (int i = 0; i < 4; ++i) rv[i] = fmaxf(acc[o][i] + bo, 0.f);
    *(float4*)&out[((size_t)(b * COUT + obase + o) * H + oy) * W + ox] =
        *(float4*)rv;
    if (WRITE_POOL) {
      float m0 = fmaxf(rv[0], rv[1]);
      float m1 = fmaxf(rv[2], rv[3]);
      float q0 = fmaxf(m0, __shfl_down(m0, 16));
      float q1 = fmaxf(m1, __shfl_down(m1, 16));
      if (((lane >> 4) & 1) == 0) {
        float2 pw; pw.x = q0; pw.y = q1;
        *(float2*)&pout[((size_t)(b * COUT + obase + o) * H2 + (oy >> 1)) * W2 +
                        (ox >> 1)] = pw;
      }
    }
  }
}

// ---------------------------------------------------------------------------
// LDS/async conv — used only by inc (unguarded harness input) and u4
// (bilinear in2 + fused 1x1+sigmoid epilogue).
// ---------------------------------------------------------------------------
template <int CIN1, int CIN2, int COUTG, int OSPLIT, bool UP_IN2, bool FUSE_OUT,
          bool WRITE_POOL>
__launch_bounds__(256)
__global__ void conv3x3_cbr(const float* __restrict__ in1,
                            const float* __restrict__ in2,
                            const float* __restrict__ wf,
                            const float* __restrict__ bf,
                            const float* __restrict__ wout,
                            const float* __restrict__ bout,
                            float* __restrict__ out,
                            float* __restrict__ pout, int H, int W) {
  constexpr int CIN = CIN1 + CIN2;
  constexpr int COUT = COUTG * OSPLIT;
  constexpr int PPT = 4;
  constexpr int CHUNK = (CIN < 4) ? CIN : 4;
  constexpr int XS = 68;
  constexpr int YT = 18;
  constexpr int ROWS = CHUNK * YT;

  __shared__ float tile[CHUNK][YT][XS];
  __shared__ float wsm[COUTG * CIN * 12];

  const int tid = threadIdx.x;
  const int txp = (tid & 15) * PPT;
  const int ty = tid >> 4;
  const int gx0 = blockIdx.x * 64;
  const int gy0 = blockIdx.y * 16;
  const int b = blockIdx.z & 7;
  const int og = blockIdx.z >> 3;
  const int obase = og * COUTG;

  const int lane = tid & 63;
  const int wv = tid >> 6;

  const int Hi = H >> 1, Wi = W >> 1;
  const float syf = UP_IN2 ? (float)(Hi - 1) / (float)(H - 1) : 0.f;

  int ux0 = 0, ux1 = 0;
  float uwx = 0.f;
  if (UP_IN2) {
    const float sx = (float)(Wi - 1) / (float)(W - 1);
    float fx = (gx0 + lane) * sx;
    ux0 = (int)fx;
    ux1 = min(ux0 + 1, Wi - 1);
    uwx = fx - (float)ux0;
  }

  for (int idx = tid; idx < COUTG * CIN * 9; idx += 256) {
    int o = idx / (CIN * 9);
    int r = idx - o * (CIN * 9);
    int c = r / 9;
    int t = r - c * 9;
    wsm[(o * CIN + c) * 12 + t] = wf[((obase + o) * CIN + c) * 9 + t];
  }

  float acc[COUTG][PPT];
#pragma unroll
  for (int o = 0; o < COUTG; ++o)
#pragma unroll
    for (int i = 0; i < PPT; ++i) acc[o][i] = 0.f;

  for (int cc = 0; cc < CIN; cc += CHUNK) {
    __syncthreads();
    if (wv < CHUNK) {
      const int c = wv;
      const int cg = cc + c;
      const bool dir1 = (CIN2 == 0 || cg < CIN1);
      if (dir1 || !UP_IN2) {
        const float* src;
        int cb;
        if (dir1) { src = in1; cb = b * CIN1 + cg; }
        else      { src = in2; cb = b * CIN2 + (cg - CIN1); }
        const float* base =
            src + (size_t)cb * H * W + (size_t)(gy0 - 1) * W + gx0 + lane;
#pragma unroll
        for (int yy = 0; yy < YT; ++yy) {
          const int iy = gy0 + yy - 1;
          if (iy >= 0 && iy < H) {
            async_row_f32(base + (size_t)yy * W, &tile[c][yy][1]);
          } else {
            tile[c][yy][1 + lane] = 0.f;
          }
        }
      } else {
        const int cb = b * CIN2 + (cg - CIN1);
#pragma unroll 1
        for (int yy = 0; yy < YT; ++yy) {
          const int iy = gy0 + yy - 1;
          float v = 0.f;
          if (iy >= 0 && iy < H) {
            float fy = iy * syf;
            int y0 = (int)fy;
            int y1 = min(y0 + 1, Hi - 1);
            float wy = fy - (float)y0;
            const float* r0p = in2 + (size_t)(cb * Hi + y0) * Wi;
            const float* r1p = in2 + (size_t)(cb * Hi + y1) * Wi;
            float a00 = r0p[ux0], a01 = r0p[ux1];
            float a10 = r1p[ux0], a11 = r1p[ux1];
            float r0 = a00 * (1.f - wy) + a10 * wy;
            float r1 = a01 * (1.f - wy) + a11 * wy;
            v = r0 * (1.f - uwx) + r1 * uwx;
          }
          tile[c][yy][1 + lane] = v;
        }
      }
    }
    for (int idx = tid; idx < 2 * ROWS; idx += 256) {
      const int row = idx >> 1;
      const int side = idx & 1;
      const int c = row / YT;
      const int yy = row - c * YT;
      const int iy = gy0 + yy - 1;
      const int ix = side ? (gx0 + 64) : (gx0 - 1);
      const int cg = cc + c;
      float v = 0.f;
      if (iy >= 0 && iy < H && ix >= 0 && ix < W) {
        if (CIN2 == 0 || cg < CIN1) {
          const int cb = b * CIN1 + cg;
          v = in1[(size_t)(cb * H + iy) * W + ix];
        } else if (UP_IN2) {
          const int cb = b * CIN2 + (cg - CIN1);
          const float sx = (float)(Wi - 1) / (float)(W - 1);
          float fy = iy * syf, fx = ix * sx;
          int y0 = (int)fy; int y1 = min(y0 + 1, Hi - 1);
          int x0 = (int)fx; int x1 = min(x0 + 1, Wi - 1);
          float wy = fy - (float)y0, wx = fx - (float)x0;
          const float* p = in2 + (size_t)cb * Hi * Wi;
          float a00 = p[y0 * Wi + x0], a01 = p[y0 * Wi + x1];
          float a10 = p[y1 * Wi + x0], a11 = p[y1 * Wi + x1];
          float r0 = a00 * (1.f - wy) + a10 * wy;
          float r1 = a01 * (1.f - wy) + a11 * wy;
          v = r0 * (1.f - wx) + r1 * wx;
        } else {
          const int cb = b * CIN2 + (cg - CIN1);
          v = in2[(size_t)(cb * H + iy) * W + ix];
        }
      }
      tile[c][yy][side ? 65 : 0] = v;
    }
    __syncthreads();
#pragma unroll
    for (int c = 0; c < CHUNK; ++c) {
      float rr[3][6];
#pragma unroll
      for (int dy = 0; dy < 3; ++dy) {
        const float* p = &tile[c][ty + dy][txp];
        float4 a4 = *(const float4*)p;
        float2 b2 = *(const float2*)(p + 4);
        rr[dy][0] = a4.x; rr[dy][1] = a4.y; rr[dy][2] = a4.z; rr[dy][3] = a4.w;
        rr[dy][4] = b2.x; rr[dy][5] = b2.y;
      }
      const int cabs = cc + c;
#pragma unroll
      for (int o = 0; o < COUTG; ++o) {
        const float4* wp = (const float4*)&wsm[(o * CIN + cabs) * 12];
        float4 wa = wp[0];
        float4 wb = wp[1];
        float w8 = wsm[(o * CIN + cabs) * 12 + 8];
#pragma unroll
        for (int i = 0; i < PPT; ++i) {
          float s = acc[o][i];
          s = fmaf(rr[0][i + 0], wa.x, s);
          s = fmaf(rr[0][i + 1], wa.y, s);
          s = fmaf(rr[0][i + 2], wa.z, s);
          s = fmaf(rr[1][i + 0], wa.w, s);
          s = fmaf(rr[1][i + 1], wb.x, s);
          s = fmaf(rr[1][i + 2], wb.y, s);
          s = fmaf(rr[2][i + 0], wb.z, s);
          s = fmaf(rr[2][i + 1], wb.w, s);
          s = fmaf(rr[2][i + 2], w8, s);
          acc[o][i] = s;
        }
      }
    }
  }

  const int oy = gy0 + ty;
  const int ox = gx0 + txp;
  if (FUSE_OUT) {
    float sv[PPT];
#pragma unroll
    for (int i = 0; i < PPT; ++i) sv[i] = bout[0];
#pragma unroll
    for (int o = 0; o < COUTG; ++o) {
      float bo = bf[obase + o], wo = wout[o];
#pragma unroll
      for (int i = 0; i < PPT; ++i) {
        float rr2 = fmaxf(acc[o][i] + bo, 0.f);
        sv[i] = fmaf(rr2, wo, sv[i]);
      }
    }
#pragma unroll
    for (int i = 0; i < PPT; ++i) sv[i] = 1.f / (1.f + __expf(-sv[i]));
    *(float4*)&out[((size_t)b * H + oy) * W + ox] = *(float4*)sv;
  } else {
    const int H2 = H >> 1, W2 = W >> 1;
#pragma unroll
    for (int o = 0; o < COUTG; ++o) {
      float bo = bf[obase + o];
      float rv[PPT];
#pragma unroll
      for (int i = 0; i < PPT; ++i) rv[i] = fmaxf(acc[o][i] + bo, 0.f);
      *(float4*)&out[((size_t)(b * COUT + obase + o) * H + oy) * W + ox] =
          *(float4*)rv;
      if (WRITE_POOL) {
        float m0 = fmaxf(rv[0], rv[1]);
        float m1 = fmaxf(rv[2], rv[3]);
        float q0 = fmaxf(m0, __shfl_down(m0, 16));
        float q1 = fmaxf(m1, __shfl_down(m1, 16));
        if (((lane >> 4) & 1) == 0) {
          float2 pw; pw.x = q0; pw.y = q1;
          *(float2*)&pout[((size_t)(b * COUT + obase + o) * H2 + (oy >> 1)) * W2 +
                          (ox >> 1)] = pw;
        }
      }
    }
  }
}

// ---------------------------------------------------------------------------
// FCAS on the 64x64 channel x4[0,1] — PARALLEL two-phase (r12: the 16-block
// O(N^2) kernel was the top dispatch at 96us, occupancy 0.67%).
// Phase 1: 256 blocks = 16 element-groups x 16 k-slices; integer partial
// counts (exact) to scratch. Phase 2: sum 16 partials, write interior
// in place (each thread reads/writes only its own index — no race).
// ---------------------------------------------------------------------------
__global__ void fcas_partial(const float* __restrict__ ch,
                             int* __restrict__ pcnt, int* __restrict__ ncnt) {
  __shared__ float sv[256];
  const int e = blockIdx.x * 256 + threadIdx.x;
  const int s = blockIdx.y;
  sv[threadIdx.x] = ch[s * 256 + threadIdx.x];
  __syncthreads();
  const float v = ch[e];
  int p = 0, n = 0;
#pragma unroll 4
  for (int k = 0; k < 256; ++k) {
    float u = sv[k];
    p += (u > v);
    n += (u == v);
  }
  pcnt[s * 4096 + e] = p;
  ncnt[s * 4096 + e] = n;
}

__global__ void fcas_final(float* __restrict__ ch,
                           const int* __restrict__ pcnt,
                           const int* __restrict__ ncnt,
                           const float* __restrict__ w,
                           const float* __restrict__ bb) {
  const int e = blockIdx.x * 256 + threadIdx.x;
  int p = 0, n = 0;
#pragma unroll
  for (int s = 0; s < 16; ++s) {
    p += pcnt[s * 4096 + e];
    n += ncnt[s * 4096 + e];
  }
  const int el = 4096 - p - n;
  float val = ((float)p * w[0] + bb[0] + (float)n * w[1] + bb[1] +
               (float)el * w[2] + bb[2]) / 3.0f;
  int i = e >> 6, j = e & 63;
  bool interior = (i >= 1) && (i <= 62) && (j >= 1) && (j <= 62);
  if (interior) ch[e] = val;
}

// ---------------------------------------------------------------------------
extern "C" void kernel_launch(void* const* d_in, const int* in_sizes, int n_in,
                              void* d_out, int out_size, void* d_ws, size_t ws_size,
                              hipStream_t stream) {
  const float* x      = (const float*)d_in[0];
  const float* w_inc  = (const float*)d_in[1];
  const float* b_inc  = (const float*)d_in[2];
  const float* g_inc  = (const float*)d_in[3];
  const float* a_inc  = (const float*)d_in[4];
  const float* w_d1   = (const float*)d_in[5];
  const float* b_d1   = (const float*)d_in[6];
  const float* g_d1   = (const float*)d_in[7];
  const float* a_d1   = (const float*)d_in[8];
  const float* w_d2   = (const float*)d_in[9];
  const float* b_d2   = (const float*)d_in[10];
  const float* g_d2   = (const float*)d_in[11];
  const float* a_d2   = (const float*)d_in[12];
  const float* w_d3   = (const float*)d_in[13];
  const float* b_d3   = (const float*)d_in[14];
  const float* g_d3   = (const float*)d_in[15];
  const float* a_d3   = (const float*)d_in[16];
  const float* w_u2   = (const float*)d_in[17];
  const float* b_u2   = (const float*)d_in[18];
  const float* g_u2   = (const float*)d_in[19];
  const float* a_u2   = (const float*)d_in[20];
  const float* w_u3   = (const float*)d_in[21];
  const float* b_u3   = (const float*)d_in[22];
  const float* g_u3   = (const float*)d_in[23];
  const float* a_u3   = (const float*)d_in[24];
  const float* w_u4   = (const float*)d_in[25];
  const float* b_u4   = (const float*)d_in[26];
  const float* g_u4   = (const float*)d_in[27];
  const float* a_u4   = (const float*)d_in[28];
  const float* w_out  = (const float*)d_in[29];
  const float* b_out  = (const float*)d_in[30];
  const float* fcas_w = (const float*)d_in[31];
  const float* fcas_b = (const float*)d_in[32];

  float* ws = (float*)d_ws;
  float* x1  = ws;                     // [8,8,512,512]   16,777,216
  float* p1  = x1 + 16777216;          // [8,8,256,256]    4,194,304
  float* x2  = p1 + 4194304;           // [8,16,256,256]   8,388,608
  float* p2  = x2 + 8388608;           // [8,16,128,128]   2,097,152
  float* x3  = p2 + 2097152;           // [8,32,128,128]   4,194,304
  float* p3  = x3 + 4194304;           // [8,32,64,64]     1,048,576
  float* x4  = p3 + 1048576;           // [8,32,64,64]     1,048,576
  float* upa = x4 + 1048576;           // [8,32,128,128]   4,194,304
  float* uo2 = upa + 4194304;          // [8,16,128,128]   2,097,152
  float* uo3 = uo2 + 2097152;          // [8,8,256,256]    4,194,304
  int*   pcnt = (int*)(uo3 + 4194304); // 16*4096 ints
  int*   ncnt = pcnt + 65536;          // 16*4096 ints
  // upb aliases [x3 ..): x3/p3/x4/upa are dead once u2 finished; uo2 beyond.
  float* upb = x3;                     // [8,16,256,256]   8,388,608 (alias)
  float* wfp = (float*)(ncnt + 65536);
  float* wf_inc = wfp;                 // 216
  float* wf_d1  = wf_inc + 216;        // 1152
  float* wf_d2  = wf_d1 + 1152;        // 4608
  float* wf_d3  = wf_d2 + 4608;        // 9216
  float* wf_u2  = wf_d3 + 9216;        // 9216
  float* wf_u3  = wf_u2 + 9216;        // 2304
  float* wf_u4  = wf_u3 + 2304;        // 576
  float* bf_inc = wf_u4 + 576;         // 8
  float* bf_d1  = bf_inc + 8;          // 16
  float* bf_d2  = bf_d1 + 16;          // 32
  float* bf_d3  = bf_d2 + 32;          // 32
  float* bf_u2  = bf_d3 + 32;          // 16
  float* bf_u3  = bf_u2 + 16;          // 8
  float* bf_u4  = bf_u3 + 8;           // 4
  float* zbuf   = bf_u4 + 4;           // 16 (16B-aligned)
  float* outp = (float*)d_out;

  AllP A;
  A.L[0] = {w_inc, b_inc, g_inc, a_inc, wf_inc, bf_inc, 8, 3};
  A.L[1] = {w_d1, b_d1, g_d1, a_d1, wf_d1, bf_d1, 16, 8};
  A.L[2] = {w_d2, b_d2, g_d2, a_d2, wf_d2, bf_d2, 32, 16};
  A.L[3] = {w_d3, b_d3, g_d3, a_d3, wf_d3, bf_d3, 32, 32};
  A.L[4] = {w_u2, b_u2, g_u2, a_u2, wf_u2, bf_u2, 16, 64};
  A.L[5] = {w_u3, b_u3, g_u3, a_u3, wf_u3, bf_u3, 8, 32};
  A.L[6] = {w_u4, b_u4, g_u4, a_u4, wf_u4, bf_u4, 4, 16};
  A.zbuf = zbuf;
  prefold_kernel<<<dim3(36, 7), dim3(256), 0, stream>>>(A);

  dim3 blk(256);
  dim3 blk2(16, 16);

  // inc: 3->8 @512, LDS/async kernel (harness input: no guard bytes), +pool
  conv3x3_cbr<3, 0, 8, 1, false, false, true><<<dim3(8, 32, 8), blk, 0, stream>>>(
      x, nullptr, wf_inc, bf_inc, nullptr, nullptr, x1, p1, 512, 512);
  // d1: p1 -> 8->16 @256, DIRECT, COUTG=4/OS4 (2048 blocks), +pool
  conv3x3_direct<8, 0, 4, 4, true><<<dim3(4, 16, 32), blk, 0, stream>>>(
      p1, nullptr, wf_d1, bf_d1, zbuf, x2, p2, 256, 256);
  // d2: p2 -> 16->32 @128, DIRECT, COUTG=4/OS8 (1024 blocks), +pool
  conv3x3_direct<16, 0, 4, 8, true><<<dim3(2, 8, 64), blk, 0, stream>>>(
      p2, nullptr, wf_d2, bf_d2, zbuf, x3, p3, 128, 128);
  // d3: p3 -> 32->32 @64, DIRECT, COUTG=2/OS16 (512 blocks)
  conv3x3_direct<32, 0, 2, 16, false><<<dim3(1, 4, 128), blk, 0, stream>>>(
      p3, nullptr, wf_d3, bf_d3, zbuf, x4, nullptr, 64, 64);
  // FCAS on x4[0,1]: parallel two-phase (256 + 16 blocks)
  fcas_partial<<<dim3(16, 16), blk, 0, stream>>>(x4 + 4096, pcnt, ncnt);
  fcas_final<<<dim3(16), blk, 0, stream>>>(x4 + 4096, pcnt, ncnt, fcas_w, fcas_b);
  // up2(x4): [8,32,64,64] -> upa [8,32,128,128]
  up2_kernel<<<dim3(8, 8, 256), blk2, 0, stream>>>(x4, upa, 64, 64);
  // u2: cat(x3, upa) 64->16 @128, DIRECT, COUTG=2/OS8 (1024 blocks)
  conv3x3_direct<32, 32, 2, 8, false><<<dim3(2, 8, 64), blk, 0, stream>>>(
      x3, upa, wf_u2, bf_u2, zbuf, uo2, nullptr, 128, 128);
  // up2(uo2): [8,16,128,128] -> upb [8,16,256,256]
  up2_kernel<<<dim3(16, 16, 128), blk2, 0, stream>>>(uo2, upb, 128, 128);
  // u3: cat(x2, upb) 32->8 @256, DIRECT, COUTG=2/OS4 (2048 blocks)
  conv3x3_direct<16, 16, 2, 4, false><<<dim3(4, 16, 32), blk, 0, stream>>>(
      x2, upb, wf_u3, bf_u3, zbuf, uo3, nullptr, 256, 256);
  // u4: cat(x1, up2(uo3)) 16->4 @512, LDS kernel, fused bilinear+1x1+sigmoid
  conv3x3_cbr<8, 8, 4, 1, true, true, false><<<dim3(8, 32, 8), blk, 0, stream>>>(
      x1, uo3, wf_u4, bf_u4, w_out, b_out, outp, nullptr, 512, 512);
}